// Round 13
// baseline (1060.769 us; speedup 1.0000x reference)
//
#include <hip/hip_runtime.h>
#include <cmath>

constexpr int N_  = 20000;
constexpr int E_  = 320000;
constexpr int NE_ = 4;
constexpr int G_  = 16;
constexpr int CAP = 96;
constexpr float RMAXF = 5.0f;
constexpr float PI_F  = 3.14159265358979323846f;
constexpr float S3  = 1.7320508075688772f;
constexpr float S5  = 2.2360679774997896f;
constexpr float S15 = 3.8729833462074170f;
constexpr float KC_ = 0.6324555320336759f; // sqrt(2/RMAX)

typedef unsigned short u16;
typedef unsigned int   u32;
typedef _Float16 f16;
typedef _Float16 f16x2 __attribute__((ext_vector_type(2)));

#define DEV static __device__ __forceinline__

// fallback scratch (440 MB) in case ws_size is too small
__device__ float g_fallback[110000000];

DEV float sigmoidf_(float x){ return 1.0f/(1.0f+__expf(-x)); }

// bf16 <-> fp32 (RTNE pack)
DEV float b2f(u16 u){ return __uint_as_float(((u32)u)<<16); }
DEV u16  f2b(float f){
  u32 x = __float_as_uint(f);
  return (u16)((x + 0x7FFFu + ((x>>16)&1u)) >> 16);
}
DEV f16x2 u2h(u32 x){ union{u32 u; f16x2 h;} v; v.u=x; return v.h; }
DEV u32 h2u(f16x2 h){ union{u32 u; f16x2 h;} v; v.h=h; return v.u; }
DEV u32 pkh(float a, float b){ f16x2 h; h.x=(f16)a; h.y=(f16)b; return h2u(h); }

DEV void st8(float* p, const float* d){
  ((float4*)p)[0] = make_float4(d[0],d[1],d[2],d[3]);
  ((float4*)p)[1] = make_float4(d[4],d[5],d[6],d[7]);
}
DEV void ld4(const float* __restrict__ p, float* d){
  float4 a = ((const float4*)p)[0];
  d[0]=a.x; d[1]=a.y; d[2]=a.z; d[3]=a.w;
}
DEV void ld4b(const u16* __restrict__ p, float* d){
  ushort4 a = *(const ushort4*)p;
  d[0]=b2f(a.x); d[1]=b2f(a.y); d[2]=b2f(a.z); d[3]=b2f(a.w);
}
DEV void st8b(u16* p, const float* d){
  uint4 v;
  v.x = (u32)f2b(d[0]) | ((u32)f2b(d[1])<<16);
  v.y = (u32)f2b(d[2]) | ((u32)f2b(d[3])<<16);
  v.z = (u32)f2b(d[4]) | ((u32)f2b(d[5])<<16);
  v.w = (u32)f2b(d[6]) | ((u32)f2b(d[7])<<16);
  *(uint4*)p = v;
}

// ---------------- CSR build (bucket lists, no scan) ----------------
__global__ void k_csr(const int* __restrict__ ei, int* __restrict__ cntR, int* __restrict__ cntS,
                      int* __restrict__ listR, int* __restrict__ listS){
  int e = blockIdx.x*256 + threadIdx.x;
  int s = ei[e], r = ei[E_+e];
  int p = atomicAdd(&cntR[r], 1); if (p < CAP) listR[r*CAP+p] = e;
  int q = atomicAdd(&cntS[s], 1); if (q < CAP) listS[s*CAP+q] = e;
}

// ---------------- weight precompute: composite matrices ----------------
__global__ void k_pre(const float* __restrict__ Wout0, const float* __restrict__ Wup1,
                      const float* __restrict__ Wskip0, const float* __restrict__ wread0,
                      float* __restrict__ WA, float* __restrict__ sa,
                      float* __restrict__ va, float* __restrict__ sv){
  int t = threadIdx.x;
  for (int idx=t; idx<4096; idx+=256){
    int c = idx>>6, d = idx&63;
    float acc=0.f;
    for (int m=0;m<64;++m) acc += Wout0[c*64+m]*Wup1[m*64+d];
    WA[idx]=acc;
  }
  {
    int k = t>>6, d = t&63;
    float acc=0.f;
    for (int m=0;m<64;++m) acc += Wskip0[k*64+m]*Wup1[m*64+d];
    sa[t]=acc;
  }
  if (t<64){
    float acc=0.f;
    for (int d=0;d<64;++d) acc += Wout0[t*64+d]*wread0[d];
    va[t]=acc;
  }
  if (t<4){
    float acc=0.f;
    for (int d=0;d<64;++d) acc += Wskip0[t*64+d]*wread0[d];
    sv[t]=acc;
  }
}

// ---------------- fused geometry + radial MLP (both layers) ----------------
__global__ __launch_bounds__(256, 2)
void k_fwd_edge(const float* __restrict__ pos, const float* __restrict__ shifts,
                const int* __restrict__ ei,
                const float* __restrict__ W1g, const float* __restrict__ W2g,
                float* __restrict__ Y, float* __restrict__ u3,
                float* __restrict__ irr,
                u16* __restrict__ R0, u16* __restrict__ R1,
                u16* __restrict__ spe0, u16* __restrict__ spe1,
                float* __restrict__ gvec){
  __shared__ float sW1[1024];   // [layer][8][64]
  __shared__ u32   sW2h[4096];  // [layer][32 kp][64 c] = half2(W2[2kp][c], W2[2kp+1][c])
  __shared__ u32   sAh[32*36];  // [edgeSlot][32 kp (+4 pad)] packed silu activations
  int t = threadIdx.x;
  for (int i=t;i<1024;i+=256) sW1[i]=W1g[i];
  for (int i=t;i<4096;i+=256){
    int L = i>>11, rem = i&2047, kp = rem>>6, c = rem&63;
    sW2h[i] = pkh(W2g[L*4096 + (2*kp)*64 + c], W2g[L*4096 + (2*kp+1)*64 + c]);
  }
  __syncthreads();
  int wid=t>>6, lane=t&63, q=lane>>3, j=lane&7, c0=j*8;
  int slot = wid*8 + q;
  int e = blockIdx.x*32 + slot;
  int snd = ei[e], rcv = ei[E_+e];
  float vx = pos[snd*3+0]-pos[rcv*3+0]+shifts[(size_t)e*3+0];
  float vy = pos[snd*3+1]-pos[rcv*3+1]+shifts[(size_t)e*3+1];
  float vz = pos[snd*3+2]-pos[rcv*3+2]+shifts[(size_t)e*3+2];
  float ss = vx*vx+vy*vy+vz*vz + 1e-12f;
  float rad = sqrtf(ss);
  float inv = 1.0f/rad;
  float x = vx*inv, y = vy*inv, z = vz*inv;
  float tt = rad*(1.0f/RMAXF);
  float fc = 0.0f, dfc = 0.0f;
  if (tt < 1.0f){
    float t2=tt*tt, t4=t2*t2, t5=t4*tt, t6=t5*tt, t7=t6*tt, t8=t7*tt;
    fc  = 1.0f - 28.0f*t6 + 48.0f*t7 - 21.0f*t8;
    dfc = (-168.0f*t5 + 336.0f*t6 - 168.0f*t7)*(1.0f/RMAXF);
  }
  float th = rad*(PI_F/RMAXF);
  float s1 = __sinf(th), c1 = __cosf(th);
  float base = KC_*inv*fc;
  float efv[8], gfv[8];
  {
    float sb = s1, cb = c1;
    #pragma unroll
    for (int b=0;b<8;++b){
      efv[b] = base*sb;
      float wb_ = (float)(b+1)*(PI_F/RMAXF);
      float rb  = KC_*sb*inv;
      float drb = KC_*(wb_*cb - sb*inv)*inv;
      gfv[b] = drb*fc + rb*dfc;
      float sn = sb*c1 + cb*s1;
      cb = cb*c1 - sb*s1;
      sb = sn;
    }
  }
  if (j==0){
    irr[e]=inv;
    u3[(size_t)e*3+0]=x; u3[(size_t)e*3+1]=y; u3[(size_t)e*3+2]=z;
    float* Ye = Y + (size_t)e*9;
    Ye[0]=1.0f;
    Ye[1]=S3*x; Ye[2]=S3*y; Ye[3]=S3*z;
    Ye[4]=S15*x*y; Ye[5]=S15*y*z;
    Ye[6]=0.5f*S5*(3.0f*z*z-1.0f);
    Ye[7]=S15*x*z;
    Ye[8]=0.5f*S15*(x*x-y*y);
    st8(gvec + (size_t)e*8, gfv);
  }
  u32* myAh = sAh + slot*36;
  for (int L=0; L<2; ++L){
    const float* w1 = sW1 + L*512;
    const u32*  w2h = sW2h + L*2048;
    float zz[8]={0,0,0,0,0,0,0,0};
    #pragma unroll 4
    for (int b=0;b<8;++b){
      float efb = efv[b];
      const float4* w=(const float4*)(w1 + b*64 + c0);
      float4 wa=w[0], wb=w[1];
      zz[0]+=efb*wa.x; zz[1]+=efb*wa.y; zz[2]+=efb*wa.z; zz[3]+=efb*wa.w;
      zz[4]+=efb*wb.x; zz[5]+=efb*wb.y; zz[6]+=efb*wb.z; zz[7]+=efb*wb.w;
    }
    float a[8], spv[8];
    #pragma unroll
    for (int i=0;i<8;++i){
      float sg = sigmoidf_(zz[i]);
      a[i]   = zz[i]*sg;
      spv[i] = sg*(1.0f + zz[i]*(1.0f - sg));
    }
    st8b((L ? spe1 : spe0) + (size_t)e*64 + c0, spv);
    {
      uint4 av;
      av.x = pkh(a[0],a[1]); av.y = pkh(a[2],a[3]);
      av.z = pkh(a[4],a[5]); av.w = pkh(a[6],a[7]);
      *(uint4*)(myAh + 4*j) = av;
    }
    float r0=0.f,r1=0.f,r2=0.f,r3=0.f,r4=0.f,r5=0.f,r6=0.f,r7=0.f;
    #pragma unroll 2
    for (int kp4=0; kp4<8; ++kp4){
      uint4 dq = *(const uint4*)(myAh + 4*kp4);
      #pragma unroll
      for (int i=0;i<4;++i){
        u32 du = (i==0)?dq.x:(i==1)?dq.y:(i==2)?dq.z:dq.w;
        f16x2 dh = u2h(du);
        const u32* wrow = w2h + (4*kp4+i)*64 + c0;
        uint4 w0 = *(const uint4*)(wrow);
        uint4 w1v = *(const uint4*)(wrow+4);
        r0 = __builtin_amdgcn_fdot2(dh, u2h(w0.x),  r0, false);
        r1 = __builtin_amdgcn_fdot2(dh, u2h(w0.y),  r1, false);
        r2 = __builtin_amdgcn_fdot2(dh, u2h(w0.z),  r2, false);
        r3 = __builtin_amdgcn_fdot2(dh, u2h(w0.w),  r3, false);
        r4 = __builtin_amdgcn_fdot2(dh, u2h(w1v.x), r4, false);
        r5 = __builtin_amdgcn_fdot2(dh, u2h(w1v.y), r5, false);
        r6 = __builtin_amdgcn_fdot2(dh, u2h(w1v.z), r6, false);
        r7 = __builtin_amdgcn_fdot2(dh, u2h(w1v.w), r7, false);
      }
    }
    float racc[8] = {r0,r1,r2,r3,r4,r5,r6,r7};
    st8b((L ? R1 : R0) + (size_t)e*64 + c0, racc);
  }
}

// ---------------- e0: LDS-binned segment sum ----------------
__global__ void k_e0(const float* __restrict__ attrs, const float* __restrict__ ae,
                     const int* __restrict__ batch, float* __restrict__ out){
  __shared__ float bins[G_];
  int t = threadIdx.x;
  if (t < G_) bins[t] = 0.f;
  __syncthreads();
  int n = blockIdx.x*256 + t;
  if (n < N_){
    float v = 0.f;
    #pragma unroll
    for (int k=0;k<NE_;++k) v += attrs[n*NE_+k]*ae[k];
    atomicAdd(&bins[batch[n]], v);
  }
  __syncthreads();
  if (t < G_){
    float b = bins[t];
    if (b != 0.f){
      atomicAdd(&out[t], b);
      atomicAdd(&out[G_ + t*3 + 0], b);
    }
  }
}

// ---------------- hu0 = attrs @ WembUp ----------------
__global__ void k_wembup(const float* __restrict__ Wemb, const float* __restrict__ Wup0,
                         float* __restrict__ WembUp){
  int t = threadIdx.x; int k = t>>6, c = t&63;
  float acc = 0.f;
  for (int j=0;j<64;++j) acc += Wemb[k*64+j]*Wup0[j*64+c];
  WembUp[k*64+c] = acc;
}

__global__ void k_hu0(const float* __restrict__ attrs, const float* __restrict__ WembUp,
                      float* __restrict__ hu0){
  int i = blockIdx.x*256 + threadIdx.x;
  int n = i>>6, c = i&63;
  float acc = 0.f;
  #pragma unroll
  for (int k=0;k<NE_;++k) acc += attrs[n*NE_+k]*WembUp[k*64+c];
  hu0[i] = acc;
}

// ---------------- agg0[n,l,c] = sum_e Y[e,l]*R0[e,c]*hu0[snd,c]  (wave/node) ----------------
__global__ void k_agg0(const int* __restrict__ cntR, const int* __restrict__ listR,
                       const int* __restrict__ ei, const float* __restrict__ hu0,
                       const u16* __restrict__ R0, const float* __restrict__ Y,
                       float* __restrict__ agg0){
  int t = threadIdx.x; int n = blockIdx.x*4 + (t>>6); int c = t&63;
  float acc[9] = {0,0,0,0,0,0,0,0,0};
  int deg = min(cntR[n], CAP);
  for (int j=0;j<deg;++j){
    int e = listR[n*CAP+j];
    int s = ei[e];
    float p = b2f(R0[(size_t)e*64+c])*hu0[(size_t)s*64+c];
    #pragma unroll
    for (int l=0;l<9;++l) acc[l] += Y[(size_t)e*9+l]*p;
  }
  #pragma unroll
  for (int l=0;l<9;++l) agg0[((size_t)n*9+l)*64+c] = acc[l];
}

// ---------------- agg1[n,c] = sum_e R1[e,c]*s1[e,c] ----------------
__global__ void k_agg1(const int* __restrict__ cntR, const int* __restrict__ listR,
                       const int* __restrict__ ei, const u16* __restrict__ hu1,
                       const u16* __restrict__ R1, const float* __restrict__ Y,
                       float* __restrict__ agg1){
  int t = threadIdx.x; int n = blockIdx.x*4 + (t>>6); int c = t&63;
  float acc = 0.f;
  int deg = min(cntR[n], CAP);
  for (int j=0;j<deg;++j){
    int e = listR[n*CAP+j];
    int s = ei[e];
    float sacc = 0.f;
    #pragma unroll
    for (int l=0;l<9;++l) sacc += b2f(hu1[((size_t)s*9+l)*64+c])*Y[(size_t)e*9+l];
    acc += b2f(R1[(size_t)e*64+c])*sacc;
  }
  agg1[(size_t)n*64+c] = acc;
}

// ---------------- dhu1[n,l,c] = sum_{snd-list} Y[e,l]*R1[e,c]*ga1[rcv,c] ----------------
__global__ void k_dhu1(const int* __restrict__ cntS, const int* __restrict__ listS,
                       const int* __restrict__ ei, const u16* __restrict__ R1,
                       const float* __restrict__ ga1, const float* __restrict__ Y,
                       float* __restrict__ dhu1){
  int t = threadIdx.x; int n = blockIdx.x*4 + (t>>6); int c = t&63;
  float acc[9] = {0,0,0,0,0,0,0,0,0};
  int deg = min(cntS[n], CAP);
  for (int j=0;j<deg;++j){
    int e = listS[n*CAP+j];
    int r = ei[E_+e];
    float ds = b2f(R1[(size_t)e*64+c])*ga1[(size_t)r*64+c];
    #pragma unroll
    for (int l=0;l<9;++l) acc[l] += Y[(size_t)e*9+l]*ds;
  }
  #pragma unroll
  for (int l=0;l<9;++l) dhu1[((size_t)n*9+l)*64+c] = acc[l];
}

// ---------------- 64x64 row-matmul v2 (wcol kk-loop MUST stay fully unrolled) ----------------
template<bool TRANS, bool OUTB>
__global__ __launch_bounds__(256, 2)
void k_mm64(const float* __restrict__ in, const float* __restrict__ W,
            void* __restrict__ out, int rows, int lper,
            const float* __restrict__ attrs, const float* __restrict__ Wsk,
            const float* __restrict__ bias){
  __shared__ float sWT[64*68];
  __shared__ float sRow[4*68];
  int t = threadIdx.x;
  for (int i=t;i<4096;i+=256){
    int k=i&63, c=i>>6;
    sWT[c*68+k] = TRANS ? W[c*64+k] : W[k*64+c];
  }
  __syncthreads();
  int wid = t>>6, c = t&63;
  float wcol[64];
  {
    const float4* wp = (const float4*)(sWT + c*68);
    #pragma unroll
    for (int kk=0;kk<16;++kk){
      float4 w4 = wp[kk];
      wcol[4*kk+0]=w4.x; wcol[4*kk+1]=w4.y; wcol[4*kk+2]=w4.z; wcol[4*kk+3]=w4.w;
    }
  }
  float* myRow = sRow + wid*68;
  for (int it=0; it<8; ++it){
    int row = (blockIdx.x*8+it)*4 + wid;
    myRow[c] = in[(size_t)row*64+c];
    float acc = 0.f;
    #pragma unroll
    for (int kk=0;kk<16;++kk){
      float4 r4 = ((const float4*)myRow)[kk];
      acc += r4.x*wcol[4*kk+0] + r4.y*wcol[4*kk+1] + r4.z*wcol[4*kk+2] + r4.w*wcol[4*kk+3];
    }
    if (lper==1 || (row % 9)==0){
      int n = (lper==1) ? row : (row/9);
      if (attrs){
        #pragma unroll
        for (int k=0;k<NE_;++k) acc += attrs[n*NE_+k]*Wsk[k*64+c];
      }
      if (bias) acc += bias[c];
    }
    if (OUTB) ((u16*)out)[(size_t)row*64+c] = f2b(acc);
    else      ((float*)out)[(size_t)row*64+c] = acc;
  }
}

// ---------------- readout 0 (from agg0, composite weights) ----------------
__global__ void k_read0(const float* __restrict__ agg0, const float* __restrict__ va,
                        const float* __restrict__ sv, const float* __restrict__ attrs,
                        const int* __restrict__ batch, float* __restrict__ out){
  __shared__ float bins[G_];
  int t = threadIdx.x;
  if (t < G_) bins[t] = 0.f;
  __syncthreads();
  int lane = t & 63, wid = t >> 6;
  int grp = lane >> 3, j = lane & 7;
  int n = blockIdx.x*32 + wid*8 + grp;
  const float* hp = agg0 + (size_t)n*576 + j*8;
  const float* wp = va + j*8;
  float4 h0 = ((const float4*)hp)[0], h4 = ((const float4*)hp)[1];
  float4 w0v = ((const float4*)wp)[0], w4v = ((const float4*)wp)[1];
  float v = h0.x*w0v.x + h0.y*w0v.y + h0.z*w0v.z + h0.w*w0v.w
          + h4.x*w4v.x + h4.y*w4v.y + h4.z*w4v.z + h4.w*w4v.w;
  v += __shfl_xor(v,1,64); v += __shfl_xor(v,2,64); v += __shfl_xor(v,4,64);
  if (j==0){
    v += attrs[n*NE_+0]*sv[0] + attrs[n*NE_+1]*sv[1]
       + attrs[n*NE_+2]*sv[2] + attrs[n*NE_+3]*sv[3];
    atomicAdd(&bins[batch[n]], v);
  }
  __syncthreads();
  if (t < G_){
    float b = bins[t];
    if (b != 0.f){
      atomicAdd(&out[t], b);
      atomicAdd(&out[G_ + t*3 + 1], b);
    }
  }
}

// ---------------- readout 1 ----------------
__global__ void k_read1(const float* __restrict__ h2, const float* __restrict__ Wr1,
                        const float* __restrict__ wr2, const int* __restrict__ batch,
                        float* __restrict__ spz, float* __restrict__ out){
  __shared__ float sW[64*16];
  __shared__ float sA[256];
  __shared__ float bins[G_];
  int t = threadIdx.x;
  for (int i=t;i<1024;i+=256) sW[i]=Wr1[i];
  if (t < G_) bins[t] = 0.f;
  __syncthreads();
  int n = blockIdx.x*16 + (t>>4); int j = t&15;
  float z = 0.f;
  #pragma unroll 16
  for (int c=0;c<64;++c) z += h2[(size_t)n*64+c]*sW[c*16+j];
  float sg = sigmoidf_(z);
  float a  = z*sg;
  float sp = sg*(1.0f + z*(1.0f - sg));
  float w2v = wr2[j];
  spz[n*16+j] = sp*w2v;
  sA[t] = a*w2v;
  __syncthreads();
  if (j==0){
    float s = 0.f;
    #pragma unroll
    for (int k=0;k<16;++k) s += sA[t+k];
    atomicAdd(&bins[batch[n]], s);
  }
  __syncthreads();
  if (t < G_){
    float b = bins[t];
    if (b != 0.f){
      atomicAdd(&out[t], b);
      atomicAdd(&out[G_ + t*3 + 2], b);
    }
  }
}

// ---------------- dh2[n,c] = sum_j Wr1[c,j]*spz[n,j] ----------------
__global__ void k_dh2(const float* __restrict__ Wr1, const float* __restrict__ spz,
                      float* __restrict__ dh2){
  int i = blockIdx.x*256 + threadIdx.x;
  int n = i>>6, c = i&63;
  float acc = 0.f;
  #pragma unroll
  for (int j=0;j<16;++j) acc += Wr1[c*16+j]*spz[n*16+j];
  dh2[i] = acc;
}

// ---------------- fused per-edge backward, BOTH layers: 16 lanes/edge, 4 edges/wave ----------------
// Shared loads (Y,u3,irr,gvec,ei) once; dy/dr partials accumulated across layers;
// single shuffle-reduction set and single force epilogue (6 atomics/edge, not 12).
__global__ __launch_bounds__(256, 2)
void k_bedgeF(const int* __restrict__ ei, const float* __restrict__ Y,
              const float* __restrict__ u3, const float* __restrict__ irr,
              const u16* __restrict__ R0, const u16* __restrict__ R1,
              const float* __restrict__ ga1, const u16* __restrict__ ga0,
              const float* __restrict__ hu0, const u16* __restrict__ hu1,
              const u16* __restrict__ spe0, const u16* __restrict__ spe1,
              const float* __restrict__ gvec,
              const float* __restrict__ W1g, const float* __restrict__ W2g,
              float* __restrict__ F){
  __shared__ float sW1[1024];    // [layer][8][64]
  __shared__ u32   sW2P[4096];   // [layer][mp][k] = half2(W2[k][2mp], W2[k][2mp+1])
  __shared__ u32   sDRh[16*32];  // [edgeSlot][mp] — reused across layers (wave-sync)
  int t = threadIdx.x;
  for (int i=t;i<1024;i+=256) sW1[i]=W1g[i];
  for (int i=t;i<4096;i+=256){
    int L=i>>11, rem=i&2047, mp=rem>>6, k=rem&63;
    sW2P[i] = pkh(W2g[L*4096 + k*64+2*mp], W2g[L*4096 + k*64+2*mp+1]);
  }
  __syncthreads();
  int wid=t>>6, lane=t&63, q=lane>>4, j=lane&15, c0=j*4;
  int slot = wid*4+q;
  int e = blockIdx.x*16 + slot;
  int snd = ei[e], rcv = ei[E_+e];
  const float4* gp = (const float4*)(gvec + (size_t)e*8);
  float4 g0v = gp[0], g1v = gp[1];
  float dyp[9];
  float drp = 0.f;
  u32* myDR = sDRh + slot*32;
  const u32* dRp = myDR;
  #pragma unroll
  for (int L=1; L>=0; --L){
    float dR[4];
    if (L==1){
      float T[4], ds[4], s[4], hu[4];
      ld4(ga1 + (size_t)rcv*64 + c0, T);
      ld4b(R1 + (size_t)e*64 + c0, ds);
      #pragma unroll
      for (int i=0;i<4;++i){ ds[i]*=T[i]; s[i]=0.f; }
      #pragma unroll
      for (int l=0;l<9;++l){
        float Yl = Y[(size_t)e*9+l];
        ld4b(hu1 + ((size_t)snd*9 + l)*64 + c0, hu);
        float p=0.f;
        #pragma unroll
        for (int i=0;i<4;++i){ s[i] += hu[i]*Yl; p += ds[i]*hu[i]; }
        dyp[l]=p;
      }
      #pragma unroll
      for (int i=0;i<4;++i) dR[i]=s[i]*T[i];
    } else {
      float s[4], P[4], T[4], g[4];
      ld4(hu0 + (size_t)snd*64 + c0, s);
      ld4b(R0 + (size_t)e*64 + c0, P);
      #pragma unroll
      for (int i=0;i<4;++i){ P[i]*=s[i]; T[i]=0.f; }
      #pragma unroll
      for (int l=0;l<9;++l){
        float Yl = Y[(size_t)e*9+l];
        ld4b(ga0 + ((size_t)rcv*9 + l)*64 + c0, g);
        float p=0.f;
        #pragma unroll
        for (int i=0;i<4;++i){ T[i]+=g[i]*Yl; p += g[i]*P[i]; }
        dyp[l]+=p;
      }
      #pragma unroll
      for (int i=0;i<4;++i) dR[i]=s[i]*T[i];
    }
    // stage dR (half2), GEMV s[k] = W2^T dR, then drp += sum_k wg[k]*sp[k]*s[k]
    *(uint2*)(myDR + 2*j) = make_uint2(pkh(dR[0],dR[1]), pkh(dR[2],dR[3]));
    const u32* w2p = sW2P + L*2048;
    float s0=0.f, s1v=0.f, s2v=0.f, s3v=0.f;
    #pragma unroll 2
    for (int mp4=0; mp4<8; ++mp4){
      uint4 dq = *(const uint4*)(dRp + 4*mp4);
      #pragma unroll
      for (int i=0;i<4;++i){
        u32 du = (i==0)?dq.x:(i==1)?dq.y:(i==2)?dq.z:dq.w;
        f16x2 dh = u2h(du);
        uint4 wq = *(const uint4*)(w2p + (4*mp4+i)*64 + c0);
        s0  = __builtin_amdgcn_fdot2(dh, u2h(wq.x), s0,  false);
        s1v = __builtin_amdgcn_fdot2(dh, u2h(wq.y), s1v, false);
        s2v = __builtin_amdgcn_fdot2(dh, u2h(wq.z), s2v, false);
        s3v = __builtin_amdgcn_fdot2(dh, u2h(wq.w), s3v, false);
      }
    }
    float wg[4]={0,0,0,0};
    {
      const float* w1b = sW1 + L*512 + c0;
      #pragma unroll 4
      for (int b=0;b<8;++b){
        float gb = (b==0)?g0v.x:(b==1)?g0v.y:(b==2)?g0v.z:(b==3)?g0v.w
                  :(b==4)?g1v.x:(b==5)?g1v.y:(b==6)?g1v.z:g1v.w;
        float4 wa = *(const float4*)(w1b + b*64);
        wg[0]+=gb*wa.x; wg[1]+=gb*wa.y; wg[2]+=gb*wa.z; wg[3]+=gb*wa.w;
      }
    }
    float spv[4];
    ld4b((L ? spe1 : spe0) + (size_t)e*64 + c0, spv);
    drp += wg[0]*spv[0]*s0 + wg[1]*spv[1]*s1v + wg[2]*spv[2]*s2v + wg[3]*spv[3]*s3v;
  }
  // single reduction set for dy[1..8] and dr
  float dy[9];
  #pragma unroll
  for (int l=1;l<9;++l){
    float v=dyp[l];
    v += __shfl_xor(v,1,64); v += __shfl_xor(v,2,64);
    v += __shfl_xor(v,4,64); v += __shfl_xor(v,8,64);
    dy[l]=v;
  }
  float dr = drp;
  dr += __shfl_xor(dr,1,64); dr += __shfl_xor(dr,2,64);
  dr += __shfl_xor(dr,4,64); dr += __shfl_xor(dr,8,64);
  float x = u3[(size_t)e*3+0], y = u3[(size_t)e*3+1], zz = u3[(size_t)e*3+2];
  float invr = irr[e];
  float dux = S3*dy[1] + S15*(y*dy[4] + zz*dy[7] + x*dy[8]);
  float duy = S3*dy[2] + S15*(x*dy[4] + zz*dy[5] - y*dy[8]);
  float duz = S3*dy[3] + S15*(y*dy[5] + x*dy[7]) + 3.0f*S5*zz*dy[6];
  float udot = x*dux + y*duy + zz*duz;
  float gx = dr*x + invr*(dux - x*udot);
  float gy = dr*y + invr*(duy - y*udot);
  float gz = dr*zz + invr*(duz - zz*udot);
  if (j==0){
    atomicAdd(&F[snd*3+0], -gx); atomicAdd(&F[snd*3+1], -gy); atomicAdd(&F[snd*3+2], -gz);
    atomicAdd(&F[rcv*3+0],  gx); atomicAdd(&F[rcv*3+1],  gy); atomicAdd(&F[rcv*3+2],  gz);
  }
}

extern "C" void kernel_launch(void* const* d_in, const int* in_sizes, int n_in,
                              void* d_out, int out_size, void* d_ws, size_t ws_size,
                              hipStream_t stream){
  (void)in_sizes; (void)n_in;
  const float* pos    = (const float*)d_in[0];
  const float* attrs  = (const float*)d_in[1];
  const float* shifts = (const float*)d_in[2];
  const float* ae     = (const float*)d_in[3];
  const float* Wemb   = (const float*)d_in[4];
  const float* Wup    = (const float*)d_in[5];
  const float* W1     = (const float*)d_in[6];
  const float* W2     = (const float*)d_in[7];
  const float* Wout   = (const float*)d_in[8];
  const float* Wskip  = (const float*)d_in[9];
  const float* wread0 = (const float*)d_in[10];
  const float* Wr1    = (const float*)d_in[11];
  const float* wr2    = (const float*)d_in[12];
  const int*   ei     = (const int*)d_in[13];
  const int*   batch  = (const int*)d_in[14];
  float* out = (float*)d_out;

  const size_t NEED = 430000000;
  char* base;
  if (ws_size >= NEED){
    base = (char*)d_ws;
  } else {
    void* p = nullptr;
    hipGetSymbolAddress(&p, HIP_SYMBOL(g_fallback));
    base = (char*)p;
  }
  size_t off = 0;
  auto alloc = [&](size_t bytes)->char*{
    char* p = base + off;
    off += ((bytes + 255)/256)*256;
    return p;
  };
  float* Y    = (float*)alloc((size_t)E_*9*4);
  float* u3   = (float*)alloc((size_t)E_*3*4);
  float* irr  = (float*)alloc((size_t)E_*4);
  u16*   R0   = (u16*)  alloc((size_t)E_*64*2);
  u16*   R1   = (u16*)  alloc((size_t)E_*64*2);
  u16*   spe0 = (u16*)  alloc((size_t)E_*64*2);
  u16*   spe1 = (u16*)  alloc((size_t)E_*64*2);
  float* gvec = (float*)alloc((size_t)E_*8*4);
  float* hu0  = (float*)alloc((size_t)N_*64*4);
  u16*   hu1  = (u16*)  alloc((size_t)N_*9*64*2);
  float* agg0 = (float*)alloc((size_t)N_*9*64*4);   // reused as dhu1
  float* agg1 = (float*)alloc((size_t)N_*64*4);
  float* h2   = (float*)alloc((size_t)N_*64*4);
  float* spz  = (float*)alloc((size_t)N_*16*4);
  float* dh2  = (float*)alloc((size_t)N_*64*4);
  float* ga1  = (float*)alloc((size_t)N_*64*4);
  u16*   ga0  = (u16*)  alloc((size_t)N_*9*64*2);
  float* WembUp = (float*)alloc(256*4);
  float* WA   = (float*)alloc(4096*4);
  float* sa   = (float*)alloc(256*4);
  float* va   = (float*)alloc(64*4);
  float* sv   = (float*)alloc(4*4);
  int* cnts  = (int*)alloc((size_t)2*N_*4);
  int* lists = (int*)alloc((size_t)2*N_*CAP*4);
  int* cntR = cnts;          int* cntS = cnts + N_;
  int* listR = lists;        int* listS = lists + (size_t)N_*CAP;
  float* dhu1 = agg0;
  float* F = out + G_ + G_*3;

  hipMemsetAsync(d_out, 0, (size_t)out_size*sizeof(float), stream);
  hipMemsetAsync(cnts, 0, (size_t)2*N_*sizeof(int), stream);

  // forward
  k_csr     <<<E_/256, 256, 0, stream>>>(ei, cntR, cntS, listR, listS);
  k_fwd_edge<<<E_/32, 256, 0, stream>>>(pos, shifts, ei, W1, W2, Y, u3, irr, R0, R1, spe0, spe1, gvec);
  k_wembup  <<<1, 256, 0, stream>>>(Wemb, Wup, WembUp);
  k_pre     <<<1, 256, 0, stream>>>(Wout, Wup + 4096, Wskip, wread0, WA, sa, va, sv);
  k_e0      <<<(N_+255)/256, 256, 0, stream>>>(attrs, ae, batch, out);
  k_hu0     <<<N_*64/256, 256, 0, stream>>>(attrs, WembUp, hu0);
  k_agg0    <<<N_/4, 256, 0, stream>>>(cntR, listR, ei, hu0, R0, Y, agg0);
  k_mm64<false,true><<<N_*9/32, 256, 0, stream>>>(agg0, WA, hu1, N_*9, 9, attrs, sa, nullptr);
  k_read0   <<<N_/32, 256, 0, stream>>>(agg0, va, sv, attrs, batch, out);
  k_agg1    <<<N_/4, 256, 0, stream>>>(cntR, listR, ei, hu1, R1, Y, agg1);
  k_mm64<false,false><<<N_/32, 256, 0, stream>>>(agg1, Wout + 4096, h2, N_, 1, attrs, Wskip + 256, nullptr);
  k_read1   <<<N_/16, 256, 0, stream>>>(h2, Wr1, wr2, batch, spz, out);

  // backward
  k_dh2     <<<N_*64/256, 256, 0, stream>>>(Wr1, spz, dh2);
  k_mm64<true,false><<<N_/32, 256, 0, stream>>>(dh2, Wout + 4096, ga1, N_, 1, nullptr, nullptr, nullptr);
  k_dhu1    <<<N_/4, 256, 0, stream>>>(cntS, listS, ei, R1, ga1, Y, dhu1);
  k_mm64<true,true><<<N_*9/32, 256, 0, stream>>>(dhu1, WA, ga0, N_*9, 9, nullptr, nullptr, va);
  k_bedgeF  <<<E_/16, 256, 0, stream>>>(ei, Y, u3, irr, R0, R1, ga1, ga0, hu0, hu1,
                                        spe0, spe1, gvec, W1, W2, F);
}

// Round 14
// 1046.071 us; speedup vs baseline: 1.0141x; 1.0141x over previous
//
#include <hip/hip_runtime.h>
#include <cmath>

constexpr int N_  = 20000;
constexpr int E_  = 320000;
constexpr int NE_ = 4;
constexpr int G_  = 16;
constexpr int CAP = 96;
constexpr float RMAXF = 5.0f;
constexpr float PI_F  = 3.14159265358979323846f;
constexpr float S3  = 1.7320508075688772f;
constexpr float S5  = 2.2360679774997896f;
constexpr float S15 = 3.8729833462074170f;
constexpr float KC_ = 0.6324555320336759f; // sqrt(2/RMAX)

typedef unsigned short u16;
typedef unsigned int   u32;
typedef _Float16 f16;
typedef _Float16 f16x2 __attribute__((ext_vector_type(2)));

#define DEV static __device__ __forceinline__

// fallback scratch (440 MB) in case ws_size is too small
__device__ float g_fallback[110000000];

DEV float sigmoidf_(float x){ return 1.0f/(1.0f+__expf(-x)); }

// bf16 <-> fp32 (RTNE pack)
DEV float b2f(u16 u){ return __uint_as_float(((u32)u)<<16); }
DEV u16  f2b(float f){
  u32 x = __float_as_uint(f);
  return (u16)((x + 0x7FFFu + ((x>>16)&1u)) >> 16);
}
DEV f16x2 u2h(u32 x){ union{u32 u; f16x2 h;} v; v.u=x; return v.h; }
DEV u32 h2u(f16x2 h){ union{u32 u; f16x2 h;} v; v.h=h; return v.u; }
DEV u32 pkh(float a, float b){ f16x2 h; h.x=(f16)a; h.y=(f16)b; return h2u(h); }

DEV void st8(float* p, const float* d){
  ((float4*)p)[0] = make_float4(d[0],d[1],d[2],d[3]);
  ((float4*)p)[1] = make_float4(d[4],d[5],d[6],d[7]);
}
DEV void ld4(const float* __restrict__ p, float* d){
  float4 a = ((const float4*)p)[0];
  d[0]=a.x; d[1]=a.y; d[2]=a.z; d[3]=a.w;
}
DEV void ld4b(const u16* __restrict__ p, float* d){
  ushort4 a = *(const ushort4*)p;
  d[0]=b2f(a.x); d[1]=b2f(a.y); d[2]=b2f(a.z); d[3]=b2f(a.w);
}
DEV void st8b(u16* p, const float* d){
  uint4 v;
  v.x = (u32)f2b(d[0]) | ((u32)f2b(d[1])<<16);
  v.y = (u32)f2b(d[2]) | ((u32)f2b(d[3])<<16);
  v.z = (u32)f2b(d[4]) | ((u32)f2b(d[5])<<16);
  v.w = (u32)f2b(d[6]) | ((u32)f2b(d[7])<<16);
  *(uint4*)p = v;
}

// ---------------- CSR build (bucket lists, no scan) ----------------
__global__ void k_csr(const int* __restrict__ ei, int* __restrict__ cntR, int* __restrict__ cntS,
                      int* __restrict__ listR, int* __restrict__ listS){
  int e = blockIdx.x*256 + threadIdx.x;
  int s = ei[e], r = ei[E_+e];
  int p = atomicAdd(&cntR[r], 1); if (p < CAP) listR[r*CAP+p] = e;
  int q = atomicAdd(&cntS[s], 1); if (q < CAP) listS[s*CAP+q] = e;
}

// ---------------- weight precompute: composite matrices ----------------
__global__ void k_pre(const float* __restrict__ Wout0, const float* __restrict__ Wup1,
                      const float* __restrict__ Wskip0, const float* __restrict__ wread0,
                      float* __restrict__ WA, float* __restrict__ sa,
                      float* __restrict__ va, float* __restrict__ sv){
  int t = threadIdx.x;
  for (int idx=t; idx<4096; idx+=256){
    int c = idx>>6, d = idx&63;
    float acc=0.f;
    for (int m=0;m<64;++m) acc += Wout0[c*64+m]*Wup1[m*64+d];
    WA[idx]=acc;
  }
  {
    int k = t>>6, d = t&63;
    float acc=0.f;
    for (int m=0;m<64;++m) acc += Wskip0[k*64+m]*Wup1[m*64+d];
    sa[t]=acc;
  }
  if (t<64){
    float acc=0.f;
    for (int d=0;d<64;++d) acc += Wout0[t*64+d]*wread0[d];
    va[t]=acc;
  }
  if (t<4){
    float acc=0.f;
    for (int d=0;d<64;++d) acc += Wskip0[t*64+d]*wread0[d];
    sv[t]=acc;
  }
}

// ---------------- fused geometry + radial MLP (both layers) ----------------
__global__ __launch_bounds__(256, 2)
void k_fwd_edge(const float* __restrict__ pos, const float* __restrict__ shifts,
                const int* __restrict__ ei,
                const float* __restrict__ W1g, const float* __restrict__ W2g,
                float* __restrict__ Y, float* __restrict__ u3,
                float* __restrict__ irr,
                u16* __restrict__ R0, u16* __restrict__ R1,
                u16* __restrict__ spe0, u16* __restrict__ spe1,
                float* __restrict__ gvec){
  __shared__ float sW1[1024];   // [layer][8][64]
  __shared__ u32   sW2h[4096];  // [layer][32 kp][64 c] = half2(W2[2kp][c], W2[2kp+1][c])
  __shared__ u32   sAh[32*36];  // [edgeSlot][32 kp (+4 pad)] packed silu activations
  int t = threadIdx.x;
  for (int i=t;i<1024;i+=256) sW1[i]=W1g[i];
  for (int i=t;i<4096;i+=256){
    int L = i>>11, rem = i&2047, kp = rem>>6, c = rem&63;
    sW2h[i] = pkh(W2g[L*4096 + (2*kp)*64 + c], W2g[L*4096 + (2*kp+1)*64 + c]);
  }
  __syncthreads();
  int wid=t>>6, lane=t&63, q=lane>>3, j=lane&7, c0=j*8;
  int slot = wid*8 + q;
  int e = blockIdx.x*32 + slot;
  int snd = ei[e], rcv = ei[E_+e];
  float vx = pos[snd*3+0]-pos[rcv*3+0]+shifts[(size_t)e*3+0];
  float vy = pos[snd*3+1]-pos[rcv*3+1]+shifts[(size_t)e*3+1];
  float vz = pos[snd*3+2]-pos[rcv*3+2]+shifts[(size_t)e*3+2];
  float ss = vx*vx+vy*vy+vz*vz + 1e-12f;
  float rad = sqrtf(ss);
  float inv = 1.0f/rad;
  float x = vx*inv, y = vy*inv, z = vz*inv;
  float tt = rad*(1.0f/RMAXF);
  float fc = 0.0f, dfc = 0.0f;
  if (tt < 1.0f){
    float t2=tt*tt, t4=t2*t2, t5=t4*tt, t6=t5*tt, t7=t6*tt, t8=t7*tt;
    fc  = 1.0f - 28.0f*t6 + 48.0f*t7 - 21.0f*t8;
    dfc = (-168.0f*t5 + 336.0f*t6 - 168.0f*t7)*(1.0f/RMAXF);
  }
  float th = rad*(PI_F/RMAXF);
  float s1 = __sinf(th), c1 = __cosf(th);
  float base = KC_*inv*fc;
  float efv[8], gfv[8];
  {
    float sb = s1, cb = c1;
    #pragma unroll
    for (int b=0;b<8;++b){
      efv[b] = base*sb;
      float wb_ = (float)(b+1)*(PI_F/RMAXF);
      float rb  = KC_*sb*inv;
      float drb = KC_*(wb_*cb - sb*inv)*inv;
      gfv[b] = drb*fc + rb*dfc;
      float sn = sb*c1 + cb*s1;
      cb = cb*c1 - sb*s1;
      sb = sn;
    }
  }
  if (j==0){
    irr[e]=inv;
    u3[(size_t)e*3+0]=x; u3[(size_t)e*3+1]=y; u3[(size_t)e*3+2]=z;
    float* Ye = Y + (size_t)e*9;
    Ye[0]=1.0f;
    Ye[1]=S3*x; Ye[2]=S3*y; Ye[3]=S3*z;
    Ye[4]=S15*x*y; Ye[5]=S15*y*z;
    Ye[6]=0.5f*S5*(3.0f*z*z-1.0f);
    Ye[7]=S15*x*z;
    Ye[8]=0.5f*S15*(x*x-y*y);
    st8(gvec + (size_t)e*8, gfv);
  }
  u32* myAh = sAh + slot*36;
  for (int L=0; L<2; ++L){
    const float* w1 = sW1 + L*512;
    const u32*  w2h = sW2h + L*2048;
    float zz[8]={0,0,0,0,0,0,0,0};
    #pragma unroll 4
    for (int b=0;b<8;++b){
      float efb = efv[b];
      const float4* w=(const float4*)(w1 + b*64 + c0);
      float4 wa=w[0], wb=w[1];
      zz[0]+=efb*wa.x; zz[1]+=efb*wa.y; zz[2]+=efb*wa.z; zz[3]+=efb*wa.w;
      zz[4]+=efb*wb.x; zz[5]+=efb*wb.y; zz[6]+=efb*wb.z; zz[7]+=efb*wb.w;
    }
    float a[8], spv[8];
    #pragma unroll
    for (int i=0;i<8;++i){
      float sg = sigmoidf_(zz[i]);
      a[i]   = zz[i]*sg;
      spv[i] = sg*(1.0f + zz[i]*(1.0f - sg));
    }
    st8b((L ? spe1 : spe0) + (size_t)e*64 + c0, spv);
    {
      uint4 av;
      av.x = pkh(a[0],a[1]); av.y = pkh(a[2],a[3]);
      av.z = pkh(a[4],a[5]); av.w = pkh(a[6],a[7]);
      *(uint4*)(myAh + 4*j) = av;
    }
    float r0=0.f,r1=0.f,r2=0.f,r3=0.f,r4=0.f,r5=0.f,r6=0.f,r7=0.f;
    #pragma unroll 2
    for (int kp4=0; kp4<8; ++kp4){
      uint4 dq = *(const uint4*)(myAh + 4*kp4);
      #pragma unroll
      for (int i=0;i<4;++i){
        u32 du = (i==0)?dq.x:(i==1)?dq.y:(i==2)?dq.z:dq.w;
        f16x2 dh = u2h(du);
        const u32* wrow = w2h + (4*kp4+i)*64 + c0;
        uint4 w0 = *(const uint4*)(wrow);
        uint4 w1v = *(const uint4*)(wrow+4);
        r0 = __builtin_amdgcn_fdot2(dh, u2h(w0.x),  r0, false);
        r1 = __builtin_amdgcn_fdot2(dh, u2h(w0.y),  r1, false);
        r2 = __builtin_amdgcn_fdot2(dh, u2h(w0.z),  r2, false);
        r3 = __builtin_amdgcn_fdot2(dh, u2h(w0.w),  r3, false);
        r4 = __builtin_amdgcn_fdot2(dh, u2h(w1v.x), r4, false);
        r5 = __builtin_amdgcn_fdot2(dh, u2h(w1v.y), r5, false);
        r6 = __builtin_amdgcn_fdot2(dh, u2h(w1v.z), r6, false);
        r7 = __builtin_amdgcn_fdot2(dh, u2h(w1v.w), r7, false);
      }
    }
    float racc[8] = {r0,r1,r2,r3,r4,r5,r6,r7};
    st8b((L ? R1 : R0) + (size_t)e*64 + c0, racc);
  }
}

// ---------------- e0: LDS-binned segment sum ----------------
__global__ void k_e0(const float* __restrict__ attrs, const float* __restrict__ ae,
                     const int* __restrict__ batch, float* __restrict__ out){
  __shared__ float bins[G_];
  int t = threadIdx.x;
  if (t < G_) bins[t] = 0.f;
  __syncthreads();
  int n = blockIdx.x*256 + t;
  if (n < N_){
    float v = 0.f;
    #pragma unroll
    for (int k=0;k<NE_;++k) v += attrs[n*NE_+k]*ae[k];
    atomicAdd(&bins[batch[n]], v);
  }
  __syncthreads();
  if (t < G_){
    float b = bins[t];
    if (b != 0.f){
      atomicAdd(&out[t], b);
      atomicAdd(&out[G_ + t*3 + 0], b);
    }
  }
}

// ---------------- hu0 = attrs @ WembUp ----------------
__global__ void k_wembup(const float* __restrict__ Wemb, const float* __restrict__ Wup0,
                         float* __restrict__ WembUp){
  int t = threadIdx.x; int k = t>>6, c = t&63;
  float acc = 0.f;
  for (int j=0;j<64;++j) acc += Wemb[k*64+j]*Wup0[j*64+c];
  WembUp[k*64+c] = acc;
}

__global__ void k_hu0(const float* __restrict__ attrs, const float* __restrict__ WembUp,
                      float* __restrict__ hu0){
  int i = blockIdx.x*256 + threadIdx.x;
  int n = i>>6, c = i&63;
  float acc = 0.f;
  #pragma unroll
  for (int k=0;k<NE_;++k) acc += attrs[n*NE_+k]*WembUp[k*64+c];
  hu0[i] = acc;
}

// ---------------- agg0[n,l,c] = sum_e Y[e,l]*R0[e,c]*hu0[snd,c]  (wave/node) ----------------
__global__ void k_agg0(const int* __restrict__ cntR, const int* __restrict__ listR,
                       const int* __restrict__ ei, const float* __restrict__ hu0,
                       const u16* __restrict__ R0, const float* __restrict__ Y,
                       float* __restrict__ agg0){
  int t = threadIdx.x; int n = blockIdx.x*4 + (t>>6); int c = t&63;
  float acc[9] = {0,0,0,0,0,0,0,0,0};
  int deg = min(cntR[n], CAP);
  for (int j=0;j<deg;++j){
    int e = listR[n*CAP+j];
    int s = ei[e];
    float p = b2f(R0[(size_t)e*64+c])*hu0[(size_t)s*64+c];
    #pragma unroll
    for (int l=0;l<9;++l) acc[l] += Y[(size_t)e*9+l]*p;
  }
  #pragma unroll
  for (int l=0;l<9;++l) agg0[((size_t)n*9+l)*64+c] = acc[l];
}

// ---------------- agg1[n,c] = sum_e R1[e,c]*s1[e,c] ----------------
__global__ void k_agg1(const int* __restrict__ cntR, const int* __restrict__ listR,
                       const int* __restrict__ ei, const u16* __restrict__ hu1,
                       const u16* __restrict__ R1, const float* __restrict__ Y,
                       float* __restrict__ agg1){
  int t = threadIdx.x; int n = blockIdx.x*4 + (t>>6); int c = t&63;
  float acc = 0.f;
  int deg = min(cntR[n], CAP);
  for (int j=0;j<deg;++j){
    int e = listR[n*CAP+j];
    int s = ei[e];
    float sacc = 0.f;
    #pragma unroll
    for (int l=0;l<9;++l) sacc += b2f(hu1[((size_t)s*9+l)*64+c])*Y[(size_t)e*9+l];
    acc += b2f(R1[(size_t)e*64+c])*sacc;
  }
  agg1[(size_t)n*64+c] = acc;
}

// ---------------- fused dhu1 + (dhu1 @ WA^T + va) -> ga0 (bf16), wave per node ----------------
// Lane c hoists WA row c into registers; 9-step wave-private LDS row exchange does the
// matmul in-kernel. Deletes the dhu1 buffer round-trip and one mm64 dispatch.
__global__ __launch_bounds__(256, 2)
void k_dhu1F(const int* __restrict__ cntS, const int* __restrict__ listS,
             const int* __restrict__ ei, const u16* __restrict__ R1,
             const float* __restrict__ ga1, const float* __restrict__ Y,
             const float* __restrict__ WA, const float* __restrict__ va,
             u16* __restrict__ ga0){
  __shared__ float sRow[4*68];
  int t = threadIdx.x; int wid = t>>6; int n = blockIdx.x*4 + wid; int c = t&63;
  float wcol[64];   // WA[c][k], k=0..63  (ga0[c] = sum_k dhu1[k]*WA[c][k])
  {
    const float4* wp = (const float4*)(WA + c*64);
    #pragma unroll
    for (int kk=0;kk<16;++kk){
      float4 w4 = wp[kk];
      wcol[4*kk+0]=w4.x; wcol[4*kk+1]=w4.y; wcol[4*kk+2]=w4.z; wcol[4*kk+3]=w4.w;
    }
  }
  float acc[9] = {0,0,0,0,0,0,0,0,0};
  int deg = min(cntS[n], CAP);
  for (int j=0;j<deg;++j){
    int e = listS[n*CAP+j];
    int r = ei[E_+e];
    float ds = b2f(R1[(size_t)e*64+c])*ga1[(size_t)r*64+c];
    #pragma unroll
    for (int l=0;l<9;++l) acc[l] += Y[(size_t)e*9+l]*ds;
  }
  float* myRow = sRow + wid*68;
  float vab = va[c];
  #pragma unroll
  for (int l=0;l<9;++l){
    myRow[c] = acc[l];          // wave-private slice; lockstep => no barrier
    float g = (l==0) ? vab : 0.f;
    #pragma unroll
    for (int kk=0;kk<16;++kk){
      float4 r4 = ((const float4*)myRow)[kk];
      g += r4.x*wcol[4*kk+0] + r4.y*wcol[4*kk+1] + r4.z*wcol[4*kk+2] + r4.w*wcol[4*kk+3];
    }
    ga0[((size_t)n*9+l)*64+c] = f2b(g);
  }
}

// ---------------- 64x64 row-matmul v2 (wcol kk-loop MUST stay fully unrolled) ----------------
template<bool TRANS, bool OUTB>
__global__ __launch_bounds__(256, 2)
void k_mm64(const float* __restrict__ in, const float* __restrict__ W,
            void* __restrict__ out, int rows, int lper,
            const float* __restrict__ attrs, const float* __restrict__ Wsk,
            const float* __restrict__ bias){
  __shared__ float sWT[64*68];
  __shared__ float sRow[4*68];
  int t = threadIdx.x;
  for (int i=t;i<4096;i+=256){
    int k=i&63, c=i>>6;
    sWT[c*68+k] = TRANS ? W[c*64+k] : W[k*64+c];
  }
  __syncthreads();
  int wid = t>>6, c = t&63;
  float wcol[64];
  {
    const float4* wp = (const float4*)(sWT + c*68);
    #pragma unroll
    for (int kk=0;kk<16;++kk){
      float4 w4 = wp[kk];
      wcol[4*kk+0]=w4.x; wcol[4*kk+1]=w4.y; wcol[4*kk+2]=w4.z; wcol[4*kk+3]=w4.w;
    }
  }
  float* myRow = sRow + wid*68;
  for (int it=0; it<8; ++it){
    int row = (blockIdx.x*8+it)*4 + wid;
    myRow[c] = in[(size_t)row*64+c];
    float acc = 0.f;
    #pragma unroll
    for (int kk=0;kk<16;++kk){
      float4 r4 = ((const float4*)myRow)[kk];
      acc += r4.x*wcol[4*kk+0] + r4.y*wcol[4*kk+1] + r4.z*wcol[4*kk+2] + r4.w*wcol[4*kk+3];
    }
    if (lper==1 || (row % 9)==0){
      int n = (lper==1) ? row : (row/9);
      if (attrs){
        #pragma unroll
        for (int k=0;k<NE_;++k) acc += attrs[n*NE_+k]*Wsk[k*64+c];
      }
      if (bias) acc += bias[c];
    }
    if (OUTB) ((u16*)out)[(size_t)row*64+c] = f2b(acc);
    else      ((float*)out)[(size_t)row*64+c] = acc;
  }
}

// ---------------- readout 0 (from agg0, composite weights) ----------------
__global__ void k_read0(const float* __restrict__ agg0, const float* __restrict__ va,
                        const float* __restrict__ sv, const float* __restrict__ attrs,
                        const int* __restrict__ batch, float* __restrict__ out){
  __shared__ float bins[G_];
  int t = threadIdx.x;
  if (t < G_) bins[t] = 0.f;
  __syncthreads();
  int lane = t & 63, wid = t >> 6;
  int grp = lane >> 3, j = lane & 7;
  int n = blockIdx.x*32 + wid*8 + grp;
  const float* hp = agg0 + (size_t)n*576 + j*8;
  const float* wp = va + j*8;
  float4 h0 = ((const float4*)hp)[0], h4 = ((const float4*)hp)[1];
  float4 w0v = ((const float4*)wp)[0], w4v = ((const float4*)wp)[1];
  float v = h0.x*w0v.x + h0.y*w0v.y + h0.z*w0v.z + h0.w*w0v.w
          + h4.x*w4v.x + h4.y*w4v.y + h4.z*w4v.z + h4.w*w4v.w;
  v += __shfl_xor(v,1,64); v += __shfl_xor(v,2,64); v += __shfl_xor(v,4,64);
  if (j==0){
    v += attrs[n*NE_+0]*sv[0] + attrs[n*NE_+1]*sv[1]
       + attrs[n*NE_+2]*sv[2] + attrs[n*NE_+3]*sv[3];
    atomicAdd(&bins[batch[n]], v);
  }
  __syncthreads();
  if (t < G_){
    float b = bins[t];
    if (b != 0.f){
      atomicAdd(&out[t], b);
      atomicAdd(&out[G_ + t*3 + 1], b);
    }
  }
}

// ---------------- readout 1 ----------------
__global__ void k_read1(const float* __restrict__ h2, const float* __restrict__ Wr1,
                        const float* __restrict__ wr2, const int* __restrict__ batch,
                        float* __restrict__ spz, float* __restrict__ out){
  __shared__ float sW[64*16];
  __shared__ float sA[256];
  __shared__ float bins[G_];
  int t = threadIdx.x;
  for (int i=t;i<1024;i+=256) sW[i]=Wr1[i];
  if (t < G_) bins[t] = 0.f;
  __syncthreads();
  int n = blockIdx.x*16 + (t>>4); int j = t&15;
  float z = 0.f;
  #pragma unroll 16
  for (int c=0;c<64;++c) z += h2[(size_t)n*64+c]*sW[c*16+j];
  float sg = sigmoidf_(z);
  float a  = z*sg;
  float sp = sg*(1.0f + z*(1.0f - sg));
  float w2v = wr2[j];
  spz[n*16+j] = sp*w2v;
  sA[t] = a*w2v;
  __syncthreads();
  if (j==0){
    float s = 0.f;
    #pragma unroll
    for (int k=0;k<16;++k) s += sA[t+k];
    atomicAdd(&bins[batch[n]], s);
  }
  __syncthreads();
  if (t < G_){
    float b = bins[t];
    if (b != 0.f){
      atomicAdd(&out[t], b);
      atomicAdd(&out[G_ + t*3 + 2], b);
    }
  }
}

// ---------------- dh2[n,c] = sum_j Wr1[c,j]*spz[n,j] ----------------
__global__ void k_dh2(const float* __restrict__ Wr1, const float* __restrict__ spz,
                      float* __restrict__ dh2){
  int i = blockIdx.x*256 + threadIdx.x;
  int n = i>>6, c = i&63;
  float acc = 0.f;
  #pragma unroll
  for (int j=0;j<16;++j) acc += Wr1[c*16+j]*spz[n*16+j];
  dh2[i] = acc;
}

// ---------------- fused per-edge backward v3 (split per layer): 16 lanes/edge ----------------
template<int LAYER>
__global__ __launch_bounds__(256, 2)
void k_bedge(const int* __restrict__ ei, const float* __restrict__ Y,
             const float* __restrict__ u3, const float* __restrict__ irr,
             const void* __restrict__ Rbuf,
             const void* __restrict__ gaBuf, const void* __restrict__ huBuf,
             const u16* __restrict__ spe, const float* __restrict__ gvec,
             const float* __restrict__ W1g, const float* __restrict__ W2g,
             float* __restrict__ F){
  __shared__ float sW1[512];
  __shared__ u32   sW2P[2048];   // [mp][k] = half2(W2[k][2mp], W2[k][2mp+1])
  __shared__ u32   sDRh[16*32];  // [edgeSlot][mp] = half2(dR[2mp], dR[2mp+1])
  int t = threadIdx.x;
  for (int i=t;i<512;i+=256)  sW1[i]=W1g[i];
  for (int i=t;i<2048;i+=256){
    int mp=i>>6, k=i&63;
    sW2P[i] = pkh(W2g[k*64+2*mp], W2g[k*64+2*mp+1]);
  }
  __syncthreads();
  int wid=t>>6, lane=t&63, q=lane>>4, j=lane&15, c0=j*4;
  int slot = wid*4+q;
  int e = blockIdx.x*16 + slot;
  int snd = ei[e], rcv = ei[E_+e];
  float dyp[9];
  float dR[4];
  if (LAYER==1){
    const u16*  Rb  = (const u16*)Rbuf;
    const float* gaf = (const float*)gaBuf;
    const u16*  hub = (const u16*)huBuf;
    float T[4], ds[4], s[4], hu[4];
    ld4(gaf + (size_t)rcv*64 + c0, T);
    ld4b(Rb + (size_t)e*64 + c0, ds);
    #pragma unroll
    for (int i=0;i<4;++i){ ds[i]*=T[i]; s[i]=0.f; }
    #pragma unroll
    for (int l=0;l<9;++l){
      float Yl = Y[(size_t)e*9+l];
      ld4b(hub + ((size_t)snd*9 + l)*64 + c0, hu);
      float p=0.f;
      #pragma unroll
      for (int i=0;i<4;++i){ s[i] += hu[i]*Yl; p += ds[i]*hu[i]; }
      dyp[l]=p;
    }
    #pragma unroll
    for (int i=0;i<4;++i) dR[i]=s[i]*T[i];
  } else {
    const u16*  Rb  = (const u16*)Rbuf;
    const u16*  gab = (const u16*)gaBuf;
    const float* huf = (const float*)huBuf;
    float s[4], P[4], T[4], g[4];
    ld4(huf + (size_t)snd*64 + c0, s);
    ld4b(Rb + (size_t)e*64 + c0, P);
    #pragma unroll
    for (int i=0;i<4;++i){ P[i]*=s[i]; T[i]=0.f; }
    #pragma unroll
    for (int l=0;l<9;++l){
      float Yl = Y[(size_t)e*9+l];
      ld4b(gab + ((size_t)rcv*9 + l)*64 + c0, g);
      float p=0.f;
      #pragma unroll
      for (int i=0;i<4;++i){ T[i]+=g[i]*Yl; p += g[i]*P[i]; }
      dyp[l]=p;
    }
    #pragma unroll
    for (int i=0;i<4;++i) dR[i]=s[i]*T[i];
  }
  float dy[9];
  #pragma unroll
  for (int l=1;l<9;++l){
    float v=dyp[l];
    v += __shfl_xor(v,1,64); v += __shfl_xor(v,2,64);
    v += __shfl_xor(v,4,64); v += __shfl_xor(v,8,64);
    dy[l]=v;
  }
  // stage dR as half2 pairs: lane owns m = c0..c0+3 -> mp = 2j, 2j+1
  {
    *(uint2*)(sDRh + slot*32 + 2*j) = make_uint2(pkh(dR[0],dR[1]), pkh(dR[2],dR[3]));
  }
  // s[k] = sum_m dR[m]*W2[k][m]  via f16 dot2 (32 m-pairs)
  float s0=0.f, s1v=0.f, s2v=0.f, s3v=0.f;
  const u32* dRp = sDRh + slot*32;
  #pragma unroll 2
  for (int mp4=0; mp4<8; ++mp4){
    uint4 dq = *(const uint4*)(dRp + 4*mp4);
    #pragma unroll
    for (int i=0;i<4;++i){
      u32 du = (i==0)?dq.x:(i==1)?dq.y:(i==2)?dq.z:dq.w;
      f16x2 dh = u2h(du);
      uint4 wq = *(const uint4*)(sW2P + (4*mp4+i)*64 + c0);
      s0  = __builtin_amdgcn_fdot2(dh, u2h(wq.x), s0,  false);
      s1v = __builtin_amdgcn_fdot2(dh, u2h(wq.y), s1v, false);
      s2v = __builtin_amdgcn_fdot2(dh, u2h(wq.z), s2v, false);
      s3v = __builtin_amdgcn_fdot2(dh, u2h(wq.w), s3v, false);
    }
  }
  // wg[k] = sum_b g_b * W1[b,k]
  const float4* gp = (const float4*)(gvec + (size_t)e*8);
  float4 g0 = gp[0], g1 = gp[1];
  float wg[4]={0,0,0,0};
  {
    const float* w1b = sW1 + c0;
    #pragma unroll 4
    for (int b=0;b<8;++b){
      float gb = (b==0)?g0.x:(b==1)?g0.y:(b==2)?g0.z:(b==3)?g0.w
                :(b==4)?g1.x:(b==5)?g1.y:(b==6)?g1.z:g1.w;
      float4 wa = *(const float4*)(w1b + b*64);
      wg[0]+=gb*wa.x; wg[1]+=gb*wa.y; wg[2]+=gb*wa.z; wg[3]+=gb*wa.w;
    }
  }
  float spv[4];
  ld4b(spe + (size_t)e*64 + c0, spv);
  float dr = wg[0]*spv[0]*s0 + wg[1]*spv[1]*s1v + wg[2]*spv[2]*s2v + wg[3]*spv[3]*s3v;
  dr += __shfl_xor(dr,1,64); dr += __shfl_xor(dr,2,64);
  dr += __shfl_xor(dr,4,64); dr += __shfl_xor(dr,8,64);
  float x = u3[(size_t)e*3+0], y = u3[(size_t)e*3+1], zz = u3[(size_t)e*3+2];
  float invr = irr[e];
  float dux = S3*dy[1] + S15*(y*dy[4] + zz*dy[7] + x*dy[8]);
  float duy = S3*dy[2] + S15*(x*dy[4] + zz*dy[5] - y*dy[8]);
  float duz = S3*dy[3] + S15*(y*dy[5] + x*dy[7]) + 3.0f*S5*zz*dy[6];
  float udot = x*dux + y*duy + zz*duz;
  float gx = dr*x + invr*(dux - x*udot);
  float gy = dr*y + invr*(duy - y*udot);
  float gz = dr*zz + invr*(duz - zz*udot);
  if (j==0){
    atomicAdd(&F[snd*3+0], -gx); atomicAdd(&F[snd*3+1], -gy); atomicAdd(&F[snd*3+2], -gz);
    atomicAdd(&F[rcv*3+0],  gx); atomicAdd(&F[rcv*3+1],  gy); atomicAdd(&F[rcv*3+2],  gz);
  }
}

extern "C" void kernel_launch(void* const* d_in, const int* in_sizes, int n_in,
                              void* d_out, int out_size, void* d_ws, size_t ws_size,
                              hipStream_t stream){
  (void)in_sizes; (void)n_in;
  const float* pos    = (const float*)d_in[0];
  const float* attrs  = (const float*)d_in[1];
  const float* shifts = (const float*)d_in[2];
  const float* ae     = (const float*)d_in[3];
  const float* Wemb   = (const float*)d_in[4];
  const float* Wup    = (const float*)d_in[5];
  const float* W1     = (const float*)d_in[6];
  const float* W2     = (const float*)d_in[7];
  const float* Wout   = (const float*)d_in[8];
  const float* Wskip  = (const float*)d_in[9];
  const float* wread0 = (const float*)d_in[10];
  const float* Wr1    = (const float*)d_in[11];
  const float* wr2    = (const float*)d_in[12];
  const int*   ei     = (const int*)d_in[13];
  const int*   batch  = (const int*)d_in[14];
  float* out = (float*)d_out;

  const size_t NEED = 430000000;
  char* base;
  if (ws_size >= NEED){
    base = (char*)d_ws;
  } else {
    void* p = nullptr;
    hipGetSymbolAddress(&p, HIP_SYMBOL(g_fallback));
    base = (char*)p;
  }
  size_t off = 0;
  auto alloc = [&](size_t bytes)->char*{
    char* p = base + off;
    off += ((bytes + 255)/256)*256;
    return p;
  };
  float* Y    = (float*)alloc((size_t)E_*9*4);
  float* u3   = (float*)alloc((size_t)E_*3*4);
  float* irr  = (float*)alloc((size_t)E_*4);
  u16*   R0   = (u16*)  alloc((size_t)E_*64*2);
  u16*   R1   = (u16*)  alloc((size_t)E_*64*2);
  u16*   spe0 = (u16*)  alloc((size_t)E_*64*2);
  u16*   spe1 = (u16*)  alloc((size_t)E_*64*2);
  float* gvec = (float*)alloc((size_t)E_*8*4);
  float* hu0  = (float*)alloc((size_t)N_*64*4);
  u16*   hu1  = (u16*)  alloc((size_t)N_*9*64*2);
  float* agg0 = (float*)alloc((size_t)N_*9*64*4);
  float* agg1 = (float*)alloc((size_t)N_*64*4);
  float* h2   = (float*)alloc((size_t)N_*64*4);
  float* spz  = (float*)alloc((size_t)N_*16*4);
  float* dh2  = (float*)alloc((size_t)N_*64*4);
  float* ga1  = (float*)alloc((size_t)N_*64*4);
  u16*   ga0  = (u16*)  alloc((size_t)N_*9*64*2);
  float* WembUp = (float*)alloc(256*4);
  float* WA   = (float*)alloc(4096*4);
  float* sa   = (float*)alloc(256*4);
  float* va   = (float*)alloc(64*4);
  float* sv   = (float*)alloc(4*4);
  int* cnts  = (int*)alloc((size_t)2*N_*4);
  int* lists = (int*)alloc((size_t)2*N_*CAP*4);
  int* cntR = cnts;          int* cntS = cnts + N_;
  int* listR = lists;        int* listS = lists + (size_t)N_*CAP;
  float* F = out + G_ + G_*3;

  hipMemsetAsync(d_out, 0, (size_t)out_size*sizeof(float), stream);
  hipMemsetAsync(cnts, 0, (size_t)2*N_*sizeof(int), stream);

  // forward
  k_csr     <<<E_/256, 256, 0, stream>>>(ei, cntR, cntS, listR, listS);
  k_fwd_edge<<<E_/32, 256, 0, stream>>>(pos, shifts, ei, W1, W2, Y, u3, irr, R0, R1, spe0, spe1, gvec);
  k_wembup  <<<1, 256, 0, stream>>>(Wemb, Wup, WembUp);
  k_pre     <<<1, 256, 0, stream>>>(Wout, Wup + 4096, Wskip, wread0, WA, sa, va, sv);
  k_e0      <<<(N_+255)/256, 256, 0, stream>>>(attrs, ae, batch, out);
  k_hu0     <<<N_*64/256, 256, 0, stream>>>(attrs, WembUp, hu0);
  k_agg0    <<<N_/4, 256, 0, stream>>>(cntR, listR, ei, hu0, R0, Y, agg0);
  k_mm64<false,true><<<N_*9/32, 256, 0, stream>>>(agg0, WA, hu1, N_*9, 9, attrs, sa, nullptr);
  k_read0   <<<N_/32, 256, 0, stream>>>(agg0, va, sv, attrs, batch, out);
  k_agg1    <<<N_/4, 256, 0, stream>>>(cntR, listR, ei, hu1, R1, Y, agg1);
  k_mm64<false,false><<<N_/32, 256, 0, stream>>>(agg1, Wout + 4096, h2, N_, 1, attrs, Wskip + 256, nullptr);
  k_read1   <<<N_/16, 256, 0, stream>>>(h2, Wr1, wr2, batch, spz, out);

  // backward
  k_dh2     <<<N_*64/256, 256, 0, stream>>>(Wr1, spz, dh2);
  k_mm64<true,false><<<N_/32, 256, 0, stream>>>(dh2, Wout + 4096, ga1, N_, 1, nullptr, nullptr, nullptr);
  k_bedge<1><<<E_/16, 256, 0, stream>>>(ei, Y, u3, irr, R1, ga1, hu1, spe1, gvec, W1 + 512, W2 + 4096, F);
  k_dhu1F   <<<N_/4, 256, 0, stream>>>(cntS, listS, ei, R1, ga1, Y, WA, va, ga0);
  k_bedge<0><<<E_/16, 256, 0, stream>>>(ei, Y, u3, irr, R0, ga0, hu0, spe0, gvec, W1, W2, F);
}

// Round 15
// 1018.909 us; speedup vs baseline: 1.0411x; 1.0267x over previous
//
#include <hip/hip_runtime.h>
#include <cmath>

constexpr int N_  = 20000;
constexpr int E_  = 320000;
constexpr int NE_ = 4;
constexpr int G_  = 16;
constexpr int CAP = 96;
constexpr float RMAXF = 5.0f;
constexpr float PI_F  = 3.14159265358979323846f;
constexpr float S3  = 1.7320508075688772f;
constexpr float S5  = 2.2360679774997896f;
constexpr float S15 = 3.8729833462074170f;
constexpr float KC_ = 0.6324555320336759f; // sqrt(2/RMAX)

typedef unsigned short u16;
typedef unsigned int   u32;
typedef _Float16 f16;
typedef _Float16 f16x2 __attribute__((ext_vector_type(2)));

#define DEV static __device__ __forceinline__

// fallback scratch (440 MB) in case ws_size is too small
__device__ float g_fallback[110000000];

DEV float sigmoidf_(float x){ return 1.0f/(1.0f+__expf(-x)); }

// bf16 <-> fp32 (RTNE pack)
DEV float b2f(u16 u){ return __uint_as_float(((u32)u)<<16); }
DEV u16  f2b(float f){
  u32 x = __float_as_uint(f);
  return (u16)((x + 0x7FFFu + ((x>>16)&1u)) >> 16);
}
DEV f16x2 u2h(u32 x){ union{u32 u; f16x2 h;} v; v.u=x; return v.h; }
DEV u32 h2u(f16x2 h){ union{u32 u; f16x2 h;} v; v.h=h; return v.u; }
DEV u32 pkh(float a, float b){ f16x2 h; h.x=(f16)a; h.y=(f16)b; return h2u(h); }

DEV void st8(float* p, const float* d){
  ((float4*)p)[0] = make_float4(d[0],d[1],d[2],d[3]);
  ((float4*)p)[1] = make_float4(d[4],d[5],d[6],d[7]);
}
DEV void ld4(const float* __restrict__ p, float* d){
  float4 a = ((const float4*)p)[0];
  d[0]=a.x; d[1]=a.y; d[2]=a.z; d[3]=a.w;
}
DEV void ld4b(const u16* __restrict__ p, float* d){
  ushort4 a = *(const ushort4*)p;
  d[0]=b2f(a.x); d[1]=b2f(a.y); d[2]=b2f(a.z); d[3]=b2f(a.w);
}
DEV void st8b(u16* p, const float* d){
  uint4 v;
  v.x = (u32)f2b(d[0]) | ((u32)f2b(d[1])<<16);
  v.y = (u32)f2b(d[2]) | ((u32)f2b(d[3])<<16);
  v.z = (u32)f2b(d[4]) | ((u32)f2b(d[5])<<16);
  v.w = (u32)f2b(d[6]) | ((u32)f2b(d[7])<<16);
  *(uint4*)p = v;
}

// ---------------- CSR build (bucket lists, no scan) ----------------
__global__ void k_csr(const int* __restrict__ ei, int* __restrict__ cntR, int* __restrict__ cntS,
                      int* __restrict__ listR, int* __restrict__ listS){
  int e = blockIdx.x*256 + threadIdx.x;
  int s = ei[e], r = ei[E_+e];
  int p = atomicAdd(&cntR[r], 1); if (p < CAP) listR[r*CAP+p] = e;
  int q = atomicAdd(&cntS[s], 1); if (q < CAP) listS[s*CAP+q] = e;
}

// ---------------- weight precompute: composite matrices ----------------
__global__ void k_pre(const float* __restrict__ Wout0, const float* __restrict__ Wup1,
                      const float* __restrict__ Wskip0, const float* __restrict__ wread0,
                      float* __restrict__ WA, float* __restrict__ sa,
                      float* __restrict__ va, float* __restrict__ sv){
  int t = threadIdx.x;
  for (int idx=t; idx<4096; idx+=256){
    int c = idx>>6, d = idx&63;
    float acc=0.f;
    for (int m=0;m<64;++m) acc += Wout0[c*64+m]*Wup1[m*64+d];
    WA[idx]=acc;
  }
  {
    int k = t>>6, d = t&63;
    float acc=0.f;
    for (int m=0;m<64;++m) acc += Wskip0[k*64+m]*Wup1[m*64+d];
    sa[t]=acc;
  }
  if (t<64){
    float acc=0.f;
    for (int d=0;d<64;++d) acc += Wout0[t*64+d]*wread0[d];
    va[t]=acc;
  }
  if (t<4){
    float acc=0.f;
    for (int d=0;d<64;++d) acc += Wskip0[t*64+d]*wread0[d];
    sv[t]=acc;
  }
}

// ---------------- fused geometry + radial MLP (both layers) ----------------
__global__ __launch_bounds__(256, 2)
void k_fwd_edge(const float* __restrict__ pos, const float* __restrict__ shifts,
                const int* __restrict__ ei,
                const float* __restrict__ W1g, const float* __restrict__ W2g,
                float* __restrict__ Y, float* __restrict__ u3,
                float* __restrict__ irr,
                u16* __restrict__ R0, u16* __restrict__ R1,
                u16* __restrict__ spe0, u16* __restrict__ spe1,
                float* __restrict__ gvec){
  __shared__ float sW1[1024];   // [layer][8][64]
  __shared__ u32   sW2h[4096];  // [layer][32 kp][64 c] = half2(W2[2kp][c], W2[2kp+1][c])
  __shared__ u32   sAh[32*36];  // [edgeSlot][32 kp (+4 pad)] packed silu activations
  int t = threadIdx.x;
  for (int i=t;i<1024;i+=256) sW1[i]=W1g[i];
  for (int i=t;i<4096;i+=256){
    int L = i>>11, rem = i&2047, kp = rem>>6, c = rem&63;
    sW2h[i] = pkh(W2g[L*4096 + (2*kp)*64 + c], W2g[L*4096 + (2*kp+1)*64 + c]);
  }
  __syncthreads();
  int wid=t>>6, lane=t&63, q=lane>>3, j=lane&7, c0=j*8;
  int slot = wid*8 + q;
  int e = blockIdx.x*32 + slot;
  int snd = ei[e], rcv = ei[E_+e];
  float vx = pos[snd*3+0]-pos[rcv*3+0]+shifts[(size_t)e*3+0];
  float vy = pos[snd*3+1]-pos[rcv*3+1]+shifts[(size_t)e*3+1];
  float vz = pos[snd*3+2]-pos[rcv*3+2]+shifts[(size_t)e*3+2];
  float ss = vx*vx+vy*vy+vz*vz + 1e-12f;
  float rad = sqrtf(ss);
  float inv = 1.0f/rad;
  float x = vx*inv, y = vy*inv, z = vz*inv;
  float tt = rad*(1.0f/RMAXF);
  float fc = 0.0f, dfc = 0.0f;
  if (tt < 1.0f){
    float t2=tt*tt, t4=t2*t2, t5=t4*tt, t6=t5*tt, t7=t6*tt, t8=t7*tt;
    fc  = 1.0f - 28.0f*t6 + 48.0f*t7 - 21.0f*t8;
    dfc = (-168.0f*t5 + 336.0f*t6 - 168.0f*t7)*(1.0f/RMAXF);
  }
  float th = rad*(PI_F/RMAXF);
  float s1 = __sinf(th), c1 = __cosf(th);
  float base = KC_*inv*fc;
  float efv[8], gfv[8];
  {
    float sb = s1, cb = c1;
    #pragma unroll
    for (int b=0;b<8;++b){
      efv[b] = base*sb;
      float wb_ = (float)(b+1)*(PI_F/RMAXF);
      float rb  = KC_*sb*inv;
      float drb = KC_*(wb_*cb - sb*inv)*inv;
      gfv[b] = drb*fc + rb*dfc;
      float sn = sb*c1 + cb*s1;
      cb = cb*c1 - sb*s1;
      sb = sn;
    }
  }
  if (j==0){
    irr[e]=inv;
    u3[(size_t)e*3+0]=x; u3[(size_t)e*3+1]=y; u3[(size_t)e*3+2]=z;
    float* Ye = Y + (size_t)e*9;
    Ye[0]=1.0f;
    Ye[1]=S3*x; Ye[2]=S3*y; Ye[3]=S3*z;
    Ye[4]=S15*x*y; Ye[5]=S15*y*z;
    Ye[6]=0.5f*S5*(3.0f*z*z-1.0f);
    Ye[7]=S15*x*z;
    Ye[8]=0.5f*S15*(x*x-y*y);
    st8(gvec + (size_t)e*8, gfv);
  }
  u32* myAh = sAh + slot*36;
  for (int L=0; L<2; ++L){
    const float* w1 = sW1 + L*512;
    const u32*  w2h = sW2h + L*2048;
    float zz[8]={0,0,0,0,0,0,0,0};
    #pragma unroll 4
    for (int b=0;b<8;++b){
      float efb = efv[b];
      const float4* w=(const float4*)(w1 + b*64 + c0);
      float4 wa=w[0], wb=w[1];
      zz[0]+=efb*wa.x; zz[1]+=efb*wa.y; zz[2]+=efb*wa.z; zz[3]+=efb*wa.w;
      zz[4]+=efb*wb.x; zz[5]+=efb*wb.y; zz[6]+=efb*wb.z; zz[7]+=efb*wb.w;
    }
    float a[8], spv[8];
    #pragma unroll
    for (int i=0;i<8;++i){
      float sg = sigmoidf_(zz[i]);
      a[i]   = zz[i]*sg;
      spv[i] = sg*(1.0f + zz[i]*(1.0f - sg));
    }
    st8b((L ? spe1 : spe0) + (size_t)e*64 + c0, spv);
    {
      uint4 av;
      av.x = pkh(a[0],a[1]); av.y = pkh(a[2],a[3]);
      av.z = pkh(a[4],a[5]); av.w = pkh(a[6],a[7]);
      *(uint4*)(myAh + 4*j) = av;
    }
    float r0=0.f,r1=0.f,r2=0.f,r3=0.f,r4=0.f,r5=0.f,r6=0.f,r7=0.f;
    #pragma unroll 2
    for (int kp4=0; kp4<8; ++kp4){
      uint4 dq = *(const uint4*)(myAh + 4*kp4);
      #pragma unroll
      for (int i=0;i<4;++i){
        u32 du = (i==0)?dq.x:(i==1)?dq.y:(i==2)?dq.z:dq.w;
        f16x2 dh = u2h(du);
        const u32* wrow = w2h + (4*kp4+i)*64 + c0;
        uint4 w0 = *(const uint4*)(wrow);
        uint4 w1v = *(const uint4*)(wrow+4);
        r0 = __builtin_amdgcn_fdot2(dh, u2h(w0.x),  r0, false);
        r1 = __builtin_amdgcn_fdot2(dh, u2h(w0.y),  r1, false);
        r2 = __builtin_amdgcn_fdot2(dh, u2h(w0.z),  r2, false);
        r3 = __builtin_amdgcn_fdot2(dh, u2h(w0.w),  r3, false);
        r4 = __builtin_amdgcn_fdot2(dh, u2h(w1v.x), r4, false);
        r5 = __builtin_amdgcn_fdot2(dh, u2h(w1v.y), r5, false);
        r6 = __builtin_amdgcn_fdot2(dh, u2h(w1v.z), r6, false);
        r7 = __builtin_amdgcn_fdot2(dh, u2h(w1v.w), r7, false);
      }
    }
    float racc[8] = {r0,r1,r2,r3,r4,r5,r6,r7};
    st8b((L ? R1 : R0) + (size_t)e*64 + c0, racc);
  }
}

// ---------------- e0: LDS-binned segment sum ----------------
__global__ void k_e0(const float* __restrict__ attrs, const float* __restrict__ ae,
                     const int* __restrict__ batch, float* __restrict__ out){
  __shared__ float bins[G_];
  int t = threadIdx.x;
  if (t < G_) bins[t] = 0.f;
  __syncthreads();
  int n = blockIdx.x*256 + t;
  if (n < N_){
    float v = 0.f;
    #pragma unroll
    for (int k=0;k<NE_;++k) v += attrs[n*NE_+k]*ae[k];
    atomicAdd(&bins[batch[n]], v);
  }
  __syncthreads();
  if (t < G_){
    float b = bins[t];
    if (b != 0.f){
      atomicAdd(&out[t], b);
      atomicAdd(&out[G_ + t*3 + 0], b);
    }
  }
}

// ---------------- hu0 = attrs @ WembUp ----------------
__global__ void k_wembup(const float* __restrict__ Wemb, const float* __restrict__ Wup0,
                         float* __restrict__ WembUp){
  int t = threadIdx.x; int k = t>>6, c = t&63;
  float acc = 0.f;
  for (int j=0;j<64;++j) acc += Wemb[k*64+j]*Wup0[j*64+c];
  WembUp[k*64+c] = acc;
}

__global__ void k_hu0(const float* __restrict__ attrs, const float* __restrict__ WembUp,
                      float* __restrict__ hu0){
  int i = blockIdx.x*256 + threadIdx.x;
  int n = i>>6, c = i&63;
  float acc = 0.f;
  #pragma unroll
  for (int k=0;k<NE_;++k) acc += attrs[n*NE_+k]*WembUp[k*64+c];
  hu0[i] = acc;
}

// ---------------- agg0[n,l,c] = sum_e Y[e,l]*R0[e,c]*hu0[snd,c]  (wave/node) ----------------
__global__ void k_agg0(const int* __restrict__ cntR, const int* __restrict__ listR,
                       const int* __restrict__ ei, const float* __restrict__ hu0,
                       const u16* __restrict__ R0, const float* __restrict__ Y,
                       float* __restrict__ agg0){
  int t = threadIdx.x; int n = blockIdx.x*4 + (t>>6); int c = t&63;
  float acc[9] = {0,0,0,0,0,0,0,0,0};
  int deg = min(cntR[n], CAP);
  for (int j=0;j<deg;++j){
    int e = listR[n*CAP+j];
    int s = ei[e];
    float p = b2f(R0[(size_t)e*64+c])*hu0[(size_t)s*64+c];
    #pragma unroll
    for (int l=0;l<9;++l) acc[l] += Y[(size_t)e*9+l]*p;
  }
  #pragma unroll
  for (int l=0;l<9;++l) agg0[((size_t)n*9+l)*64+c] = acc[l];
}

// ---------------- agg1[n,c] = sum_e R1[e,c]*s1[e,c] ----------------
__global__ void k_agg1(const int* __restrict__ cntR, const int* __restrict__ listR,
                       const int* __restrict__ ei, const u16* __restrict__ hu1,
                       const u16* __restrict__ R1, const float* __restrict__ Y,
                       float* __restrict__ agg1){
  int t = threadIdx.x; int n = blockIdx.x*4 + (t>>6); int c = t&63;
  float acc = 0.f;
  int deg = min(cntR[n], CAP);
  for (int j=0;j<deg;++j){
    int e = listR[n*CAP+j];
    int s = ei[e];
    float sacc = 0.f;
    #pragma unroll
    for (int l=0;l<9;++l) sacc += b2f(hu1[((size_t)s*9+l)*64+c])*Y[(size_t)e*9+l];
    acc += b2f(R1[(size_t)e*64+c])*sacc;
  }
  agg1[(size_t)n*64+c] = acc;
}

// ---------------- dhu1[n,l,c] = sum_{snd-list} Y[e,l]*R1[e,c]*ga1[rcv,c] ----------------
// Lean (20 VGPR) gather kernel — keep the matmul OUT of here (R14 regression).
__global__ void k_dhu1(const int* __restrict__ cntS, const int* __restrict__ listS,
                       const int* __restrict__ ei, const u16* __restrict__ R1,
                       const float* __restrict__ ga1, const float* __restrict__ Y,
                       float* __restrict__ dhu1){
  int t = threadIdx.x; int n = blockIdx.x*4 + (t>>6); int c = t&63;
  float acc[9] = {0,0,0,0,0,0,0,0,0};
  int deg = min(cntS[n], CAP);
  for (int j=0;j<deg;++j){
    int e = listS[n*CAP+j];
    int r = ei[E_+e];
    float ds = b2f(R1[(size_t)e*64+c])*ga1[(size_t)r*64+c];
    #pragma unroll
    for (int l=0;l<9;++l) acc[l] += Y[(size_t)e*9+l]*ds;
  }
  #pragma unroll
  for (int l=0;l<9;++l) dhu1[((size_t)n*9+l)*64+c] = acc[l];
}

// ---------------- 64x64 row-matmul v2 (wcol kk-loop MUST stay fully unrolled) ----------------
template<bool TRANS, bool OUTB>
__global__ __launch_bounds__(256, 2)
void k_mm64(const float* __restrict__ in, const float* __restrict__ W,
            void* __restrict__ out, int rows, int lper,
            const float* __restrict__ attrs, const float* __restrict__ Wsk,
            const float* __restrict__ bias){
  __shared__ float sWT[64*68];
  __shared__ float sRow[4*68];
  int t = threadIdx.x;
  for (int i=t;i<4096;i+=256){
    int k=i&63, c=i>>6;
    sWT[c*68+k] = TRANS ? W[c*64+k] : W[k*64+c];
  }
  __syncthreads();
  int wid = t>>6, c = t&63;
  float wcol[64];
  {
    const float4* wp = (const float4*)(sWT + c*68);
    #pragma unroll
    for (int kk=0;kk<16;++kk){
      float4 w4 = wp[kk];
      wcol[4*kk+0]=w4.x; wcol[4*kk+1]=w4.y; wcol[4*kk+2]=w4.z; wcol[4*kk+3]=w4.w;
    }
  }
  float* myRow = sRow + wid*68;
  for (int it=0; it<8; ++it){
    int row = (blockIdx.x*8+it)*4 + wid;
    myRow[c] = in[(size_t)row*64+c];
    float acc = 0.f;
    #pragma unroll
    for (int kk=0;kk<16;++kk){
      float4 r4 = ((const float4*)myRow)[kk];
      acc += r4.x*wcol[4*kk+0] + r4.y*wcol[4*kk+1] + r4.z*wcol[4*kk+2] + r4.w*wcol[4*kk+3];
    }
    if (lper==1 || (row % 9)==0){
      int n = (lper==1) ? row : (row/9);
      if (attrs){
        #pragma unroll
        for (int k=0;k<NE_;++k) acc += attrs[n*NE_+k]*Wsk[k*64+c];
      }
      if (bias) acc += bias[c];
    }
    if (OUTB) ((u16*)out)[(size_t)row*64+c] = f2b(acc);
    else      ((float*)out)[(size_t)row*64+c] = acc;
  }
}

// ---------------- readout 0 (from agg0, composite weights) ----------------
__global__ void k_read0(const float* __restrict__ agg0, const float* __restrict__ va,
                        const float* __restrict__ sv, const float* __restrict__ attrs,
                        const int* __restrict__ batch, float* __restrict__ out){
  __shared__ float bins[G_];
  int t = threadIdx.x;
  if (t < G_) bins[t] = 0.f;
  __syncthreads();
  int lane = t & 63, wid = t >> 6;
  int grp = lane >> 3, j = lane & 7;
  int n = blockIdx.x*32 + wid*8 + grp;
  const float* hp = agg0 + (size_t)n*576 + j*8;
  const float* wp = va + j*8;
  float4 h0 = ((const float4*)hp)[0], h4 = ((const float4*)hp)[1];
  float4 w0v = ((const float4*)wp)[0], w4v = ((const float4*)wp)[1];
  float v = h0.x*w0v.x + h0.y*w0v.y + h0.z*w0v.z + h0.w*w0v.w
          + h4.x*w4v.x + h4.y*w4v.y + h4.z*w4v.z + h4.w*w4v.w;
  v += __shfl_xor(v,1,64); v += __shfl_xor(v,2,64); v += __shfl_xor(v,4,64);
  if (j==0){
    v += attrs[n*NE_+0]*sv[0] + attrs[n*NE_+1]*sv[1]
       + attrs[n*NE_+2]*sv[2] + attrs[n*NE_+3]*sv[3];
    atomicAdd(&bins[batch[n]], v);
  }
  __syncthreads();
  if (t < G_){
    float b = bins[t];
    if (b != 0.f){
      atomicAdd(&out[t], b);
      atomicAdd(&out[G_ + t*3 + 1], b);
    }
  }
}

// ---------------- readout 1 ----------------
__global__ void k_read1(const float* __restrict__ h2, const float* __restrict__ Wr1,
                        const float* __restrict__ wr2, const int* __restrict__ batch,
                        float* __restrict__ spz, float* __restrict__ out){
  __shared__ float sW[64*16];
  __shared__ float sA[256];
  __shared__ float bins[G_];
  int t = threadIdx.x;
  for (int i=t;i<1024;i+=256) sW[i]=Wr1[i];
  if (t < G_) bins[t] = 0.f;
  __syncthreads();
  int n = blockIdx.x*16 + (t>>4); int j = t&15;
  float z = 0.f;
  #pragma unroll 16
  for (int c=0;c<64;++c) z += h2[(size_t)n*64+c]*sW[c*16+j];
  float sg = sigmoidf_(z);
  float a  = z*sg;
  float sp = sg*(1.0f + z*(1.0f - sg));
  float w2v = wr2[j];
  spz[n*16+j] = sp*w2v;
  sA[t] = a*w2v;
  __syncthreads();
  if (j==0){
    float s = 0.f;
    #pragma unroll
    for (int k=0;k<16;++k) s += sA[t+k];
    atomicAdd(&bins[batch[n]], s);
  }
  __syncthreads();
  if (t < G_){
    float b = bins[t];
    if (b != 0.f){
      atomicAdd(&out[t], b);
      atomicAdd(&out[G_ + t*3 + 2], b);
    }
  }
}

// ---------------- dh2[n,c] = sum_j Wr1[c,j]*spz[n,j] ----------------
__global__ void k_dh2(const float* __restrict__ Wr1, const float* __restrict__ spz,
                      float* __restrict__ dh2){
  int i = blockIdx.x*256 + threadIdx.x;
  int n = i>>6, c = i&63;
  float acc = 0.f;
  #pragma unroll
  for (int j=0;j<16;++j) acc += Wr1[c*16+j]*spz[n*16+j];
  dh2[i] = acc;
}

// ---------------- fused per-edge backward v3 (split per layer): 16 lanes/edge ----------------
template<int LAYER>
__global__ __launch_bounds__(256, 2)
void k_bedge(const int* __restrict__ ei, const float* __restrict__ Y,
             const float* __restrict__ u3, const float* __restrict__ irr,
             const void* __restrict__ Rbuf,
             const void* __restrict__ gaBuf, const void* __restrict__ huBuf,
             const u16* __restrict__ spe, const float* __restrict__ gvec,
             const float* __restrict__ W1g, const float* __restrict__ W2g,
             float* __restrict__ F){
  __shared__ float sW1[512];
  __shared__ u32   sW2P[2048];   // [mp][k] = half2(W2[k][2mp], W2[k][2mp+1])
  __shared__ u32   sDRh[16*32];  // [edgeSlot][mp] = half2(dR[2mp], dR[2mp+1])
  int t = threadIdx.x;
  for (int i=t;i<512;i+=256)  sW1[i]=W1g[i];
  for (int i=t;i<2048;i+=256){
    int mp=i>>6, k=i&63;
    sW2P[i] = pkh(W2g[k*64+2*mp], W2g[k*64+2*mp+1]);
  }
  __syncthreads();
  int wid=t>>6, lane=t&63, q=lane>>4, j=lane&15, c0=j*4;
  int slot = wid*4+q;
  int e = blockIdx.x*16 + slot;
  int snd = ei[e], rcv = ei[E_+e];
  float dyp[9];
  float dR[4];
  if (LAYER==1){
    const u16*  Rb  = (const u16*)Rbuf;
    const float* gaf = (const float*)gaBuf;
    const u16*  hub = (const u16*)huBuf;
    float T[4], ds[4], s[4], hu[4];
    ld4(gaf + (size_t)rcv*64 + c0, T);
    ld4b(Rb + (size_t)e*64 + c0, ds);
    #pragma unroll
    for (int i=0;i<4;++i){ ds[i]*=T[i]; s[i]=0.f; }
    #pragma unroll
    for (int l=0;l<9;++l){
      float Yl = Y[(size_t)e*9+l];
      ld4b(hub + ((size_t)snd*9 + l)*64 + c0, hu);
      float p=0.f;
      #pragma unroll
      for (int i=0;i<4;++i){ s[i] += hu[i]*Yl; p += ds[i]*hu[i]; }
      dyp[l]=p;
    }
    #pragma unroll
    for (int i=0;i<4;++i) dR[i]=s[i]*T[i];
  } else {
    const u16*  Rb  = (const u16*)Rbuf;
    const u16*  gab = (const u16*)gaBuf;
    const float* huf = (const float*)huBuf;
    float s[4], P[4], T[4], g[4];
    ld4(huf + (size_t)snd*64 + c0, s);
    ld4b(Rb + (size_t)e*64 + c0, P);
    #pragma unroll
    for (int i=0;i<4;++i){ P[i]*=s[i]; T[i]=0.f; }
    #pragma unroll
    for (int l=0;l<9;++l){
      float Yl = Y[(size_t)e*9+l];
      ld4b(gab + ((size_t)rcv*9 + l)*64 + c0, g);
      float p=0.f;
      #pragma unroll
      for (int i=0;i<4;++i){ T[i]+=g[i]*Yl; p += g[i]*P[i]; }
      dyp[l]=p;
    }
    #pragma unroll
    for (int i=0;i<4;++i) dR[i]=s[i]*T[i];
  }
  float dy[9];
  #pragma unroll
  for (int l=1;l<9;++l){
    float v=dyp[l];
    v += __shfl_xor(v,1,64); v += __shfl_xor(v,2,64);
    v += __shfl_xor(v,4,64); v += __shfl_xor(v,8,64);
    dy[l]=v;
  }
  // stage dR as half2 pairs: lane owns m = c0..c0+3 -> mp = 2j, 2j+1
  {
    *(uint2*)(sDRh + slot*32 + 2*j) = make_uint2(pkh(dR[0],dR[1]), pkh(dR[2],dR[3]));
  }
  // s[k] = sum_m dR[m]*W2[k][m]  via f16 dot2 (32 m-pairs)
  float s0=0.f, s1v=0.f, s2v=0.f, s3v=0.f;
  const u32* dRp = sDRh + slot*32;
  #pragma unroll 2
  for (int mp4=0; mp4<8; ++mp4){
    uint4 dq = *(const uint4*)(dRp + 4*mp4);
    #pragma unroll
    for (int i=0;i<4;++i){
      u32 du = (i==0)?dq.x:(i==1)?dq.y:(i==2)?dq.z:dq.w;
      f16x2 dh = u2h(du);
      uint4 wq = *(const uint4*)(sW2P + (4*mp4+i)*64 + c0);
      s0  = __builtin_amdgcn_fdot2(dh, u2h(wq.x), s0,  false);
      s1v = __builtin_amdgcn_fdot2(dh, u2h(wq.y), s1v, false);
      s2v = __builtin_amdgcn_fdot2(dh, u2h(wq.z), s2v, false);
      s3v = __builtin_amdgcn_fdot2(dh, u2h(wq.w), s3v, false);
    }
  }
  // wg[k] = sum_b g_b * W1[b,k]
  const float4* gp = (const float4*)(gvec + (size_t)e*8);
  float4 g0 = gp[0], g1 = gp[1];
  float wg[4]={0,0,0,0};
  {
    const float* w1b = sW1 + c0;
    #pragma unroll 4
    for (int b=0;b<8;++b){
      float gb = (b==0)?g0.x:(b==1)?g0.y:(b==2)?g0.z:(b==3)?g0.w
                :(b==4)?g1.x:(b==5)?g1.y:(b==6)?g1.z:g1.w;
      float4 wa = *(const float4*)(w1b + b*64);
      wg[0]+=gb*wa.x; wg[1]+=gb*wa.y; wg[2]+=gb*wa.z; wg[3]+=gb*wa.w;
    }
  }
  float spv[4];
  ld4b(spe + (size_t)e*64 + c0, spv);
  float dr = wg[0]*spv[0]*s0 + wg[1]*spv[1]*s1v + wg[2]*spv[2]*s2v + wg[3]*spv[3]*s3v;
  dr += __shfl_xor(dr,1,64); dr += __shfl_xor(dr,2,64);
  dr += __shfl_xor(dr,4,64); dr += __shfl_xor(dr,8,64);
  float x = u3[(size_t)e*3+0], y = u3[(size_t)e*3+1], zz = u3[(size_t)e*3+2];
  float invr = irr[e];
  float dux = S3*dy[1] + S15*(y*dy[4] + zz*dy[7] + x*dy[8]);
  float duy = S3*dy[2] + S15*(x*dy[4] + zz*dy[5] - y*dy[8]);
  float duz = S3*dy[3] + S15*(y*dy[5] + x*dy[7]) + 3.0f*S5*zz*dy[6];
  float udot = x*dux + y*duy + zz*duz;
  float gx = dr*x + invr*(dux - x*udot);
  float gy = dr*y + invr*(duy - y*udot);
  float gz = dr*zz + invr*(duz - zz*udot);
  if (j==0){
    atomicAdd(&F[snd*3+0], -gx); atomicAdd(&F[snd*3+1], -gy); atomicAdd(&F[snd*3+2], -gz);
    atomicAdd(&F[rcv*3+0],  gx); atomicAdd(&F[rcv*3+1],  gy); atomicAdd(&F[rcv*3+2],  gz);
  }
}

extern "C" void kernel_launch(void* const* d_in, const int* in_sizes, int n_in,
                              void* d_out, int out_size, void* d_ws, size_t ws_size,
                              hipStream_t stream){
  (void)in_sizes; (void)n_in;
  const float* pos    = (const float*)d_in[0];
  const float* attrs  = (const float*)d_in[1];
  const float* shifts = (const float*)d_in[2];
  const float* ae     = (const float*)d_in[3];
  const float* Wemb   = (const float*)d_in[4];
  const float* Wup    = (const float*)d_in[5];
  const float* W1     = (const float*)d_in[6];
  const float* W2     = (const float*)d_in[7];
  const float* Wout   = (const float*)d_in[8];
  const float* Wskip  = (const float*)d_in[9];
  const float* wread0 = (const float*)d_in[10];
  const float* Wr1    = (const float*)d_in[11];
  const float* wr2    = (const float*)d_in[12];
  const int*   ei     = (const int*)d_in[13];
  const int*   batch  = (const int*)d_in[14];
  float* out = (float*)d_out;

  const size_t NEED = 430000000;
  char* base;
  if (ws_size >= NEED){
    base = (char*)d_ws;
  } else {
    void* p = nullptr;
    hipGetSymbolAddress(&p, HIP_SYMBOL(g_fallback));
    base = (char*)p;
  }
  size_t off = 0;
  auto alloc = [&](size_t bytes)->char*{
    char* p = base + off;
    off += ((bytes + 255)/256)*256;
    return p;
  };
  float* Y    = (float*)alloc((size_t)E_*9*4);
  float* u3   = (float*)alloc((size_t)E_*3*4);
  float* irr  = (float*)alloc((size_t)E_*4);
  u16*   R0   = (u16*)  alloc((size_t)E_*64*2);
  u16*   R1   = (u16*)  alloc((size_t)E_*64*2);
  u16*   spe0 = (u16*)  alloc((size_t)E_*64*2);
  u16*   spe1 = (u16*)  alloc((size_t)E_*64*2);
  float* gvec = (float*)alloc((size_t)E_*8*4);
  float* hu0  = (float*)alloc((size_t)N_*64*4);
  u16*   hu1  = (u16*)  alloc((size_t)N_*9*64*2);
  float* agg0 = (float*)alloc((size_t)N_*9*64*4);   // reused as dhu1
  float* agg1 = (float*)alloc((size_t)N_*64*4);
  float* h2   = (float*)alloc((size_t)N_*64*4);
  float* spz  = (float*)alloc((size_t)N_*16*4);
  float* dh2  = (float*)alloc((size_t)N_*64*4);
  float* ga1  = (float*)alloc((size_t)N_*64*4);
  u16*   ga0  = (u16*)  alloc((size_t)N_*9*64*2);
  float* WembUp = (float*)alloc(256*4);
  float* WA   = (float*)alloc(4096*4);
  float* sa   = (float*)alloc(256*4);
  float* va   = (float*)alloc(64*4);
  float* sv   = (float*)alloc(4*4);
  int* cnts  = (int*)alloc((size_t)2*N_*4);
  int* lists = (int*)alloc((size_t)2*N_*CAP*4);
  int* cntR = cnts;          int* cntS = cnts + N_;
  int* listR = lists;        int* listS = lists + (size_t)N_*CAP;
  float* dhu1 = agg0;
  float* F = out + G_ + G_*3;

  hipMemsetAsync(d_out, 0, (size_t)out_size*sizeof(float), stream);
  hipMemsetAsync(cnts, 0, (size_t)2*N_*sizeof(int), stream);

  // forward
  k_csr     <<<E_/256, 256, 0, stream>>>(ei, cntR, cntS, listR, listS);
  k_fwd_edge<<<E_/32, 256, 0, stream>>>(pos, shifts, ei, W1, W2, Y, u3, irr, R0, R1, spe0, spe1, gvec);
  k_wembup  <<<1, 256, 0, stream>>>(Wemb, Wup, WembUp);
  k_pre     <<<1, 256, 0, stream>>>(Wout, Wup + 4096, Wskip, wread0, WA, sa, va, sv);
  k_e0      <<<(N_+255)/256, 256, 0, stream>>>(attrs, ae, batch, out);
  k_hu0     <<<N_*64/256, 256, 0, stream>>>(attrs, WembUp, hu0);
  k_agg0    <<<N_/4, 256, 0, stream>>>(cntR, listR, ei, hu0, R0, Y, agg0);
  k_mm64<false,true><<<N_*9/32, 256, 0, stream>>>(agg0, WA, hu1, N_*9, 9, attrs, sa, nullptr);
  k_read0   <<<N_/32, 256, 0, stream>>>(agg0, va, sv, attrs, batch, out);
  k_agg1    <<<N_/4, 256, 0, stream>>>(cntR, listR, ei, hu1, R1, Y, agg1);
  k_mm64<false,false><<<N_/32, 256, 0, stream>>>(agg1, Wout + 4096, h2, N_, 1, attrs, Wskip + 256, nullptr);
  k_read1   <<<N_/16, 256, 0, stream>>>(h2, Wr1, wr2, batch, spz, out);

  // backward
  k_dh2     <<<N_*64/256, 256, 0, stream>>>(Wr1, spz, dh2);
  k_mm64<true,false><<<N_/32, 256, 0, stream>>>(dh2, Wout + 4096, ga1, N_, 1, nullptr, nullptr, nullptr);
  k_bedge<1><<<E_/16, 256, 0, stream>>>(ei, Y, u3, irr, R1, ga1, hu1, spe1, gvec, W1 + 512, W2 + 4096, F);
  k_dhu1    <<<N_/4, 256, 0, stream>>>(cntS, listS, ei, R1, ga1, Y, dhu1);
  k_mm64<true,true><<<N_*9/32, 256, 0, stream>>>(dhu1, WA, ga0, N_*9, 9, nullptr, nullptr, va);
  k_bedge<0><<<E_/16, 256, 0, stream>>>(ei, Y, u3, irr, R0, ga0, hu0, spe0, gvec, W1, W2, F);
}